// Round 1
// baseline (7679.695 us; speedup 1.0000x reference)
//
#include <hip/hip_runtime.h>
#include <math.h>

#define Hd 5
#define NN 20000
#define EE 320000
#define NBATCH 4
#define BNH (NBATCH * NN * Hd) /* 400000 */

__device__ __forceinline__ float sigmoidf_(float v) {
    return 1.0f / (1.0f + expf(-v));
}

// ---------------------------------------------------------------------------
// transpose 64x64 (row-major src -> dst[q*64+j] = src[j*64+q])
// ---------------------------------------------------------------------------
__global__ void transpose64(const float* __restrict__ src, float* __restrict__ dst) {
    int t = blockIdx.x * 256 + threadIdx.x; // 4096 threads
    int j = t >> 6;
    int q = t & 63;
    dst[q * 64 + j] = src[j * 64 + q];
}

// ---------------------------------------------------------------------------
// message MLP: x[9] -> 64 (relu) -> 64 (relu) -> 5
// W2T is transposed (column-contiguous) so uniform scalar loads are wide.
// ---------------------------------------------------------------------------
__device__ __forceinline__ void msg_mlp(
    const float* __restrict__ x,
    const float* __restrict__ W1, const float* __restrict__ b1,
    const float* __restrict__ W2T, const float* __restrict__ b2,
    const float* __restrict__ W3, const float* __restrict__ b3,
    float* __restrict__ out)
{
    float a1[64];
#pragma unroll
    for (int k = 0; k < 64; ++k) {
        float t = b1[k];
#pragma unroll
        for (int j = 0; j < 9; ++j) t = fmaf(x[j], W1[j * 64 + k], t);
        a1[k] = fmaxf(t, 0.0f);
    }
    float acc[Hd];
#pragma unroll
    for (int i = 0; i < Hd; ++i) acc[i] = b3[i];
#pragma unroll 1
    for (int q = 0; q < 64; ++q) {   // wave-uniform -> scalar weight loads
        float t = b2[q];
        const float* wc = W2T + q * 64;
#pragma unroll
        for (int j = 0; j < 64; ++j) t = fmaf(a1[j], wc[j], t);
        t = fmaxf(t, 0.0f);
#pragma unroll
        for (int i = 0; i < Hd; ++i) acc[i] = fmaf(t, W3[q * Hd + i], acc[i]);
    }
#pragma unroll
    for (int i = 0; i < Hd; ++i) out[i] = acc[i];
}

// ---------------------------------------------------------------------------
// per-edge message kernel: computes me0 (from h0) and me1 (from h1),
// atomically accumulates into s0 / s1 at index_out.
// grid: (EE/256, NBATCH)
// ---------------------------------------------------------------------------
__global__ void msg_kernel(
    const float* __restrict__ Jm, const float* __restrict__ bnode,
    const int* __restrict__ iin, const int* __restrict__ iout,
    const float* __restrict__ W1, const float* __restrict__ b1,
    const float* __restrict__ W2T, const float* __restrict__ b2,
    const float* __restrict__ W3, const float* __restrict__ b3,
    const float* __restrict__ h0, const float* __restrict__ h1,
    float* __restrict__ s0, float* __restrict__ s1)
{
    int e = blockIdx.x * 256 + threadIdx.x;
    int bb = blockIdx.y;
    int io = iout[e];
    int ii = iin[e];
    float bin  = bnode[bb * NN + ii];
    float bout = bnode[bb * NN + io];
    float jm   = Jm[(size_t)bb * EE + e];
    size_t hoff = ((size_t)bb * NN + io) * Hd;

    float x[9];
    x[5] = bin; x[6] = bout; x[7] = jm; x[8] = -jm;

#pragma unroll
    for (int i = 0; i < Hd; ++i) x[i] = h0[hoff + i];
    float me0[Hd];
    msg_mlp(x, W1, b1, W2T, b2, W3, b3, me0);

#pragma unroll
    for (int i = 0; i < Hd; ++i) x[i] = h1[hoff + i];
    float me1[Hd];
    msg_mlp(x, W1, b1, W2T, b2, W3, b3, me1);

#pragma unroll
    for (int i = 0; i < Hd; ++i) atomicAdd(&s0[hoff + i], me0[i]);
#pragma unroll
    for (int i = 0; i < Hd; ++i) atomicAdd(&s1[hoff + i], me1[i]);
}

// ---------------------------------------------------------------------------
// per-node GRU update.
// m0 += s0 ; m1 = m0_new + s1 (m0 persists across steps, m1 rebuilt)
// a = [h1, m0, m1]; z = sig(a@gzW+gzb); r = sig(a@grW+grb)
// h_hat = tanh([r*h1, m0, m1]@ghW+ghb); h_new = (1-z)*h1 + z*h_hat
// h0 <- h1 ; h1 <- h_new ; s0,s1 <- 0 (for next step)
// ---------------------------------------------------------------------------
__global__ void node_kernel(
    const float* __restrict__ gzW, const float* __restrict__ gzb,
    const float* __restrict__ grW, const float* __restrict__ grb,
    const float* __restrict__ ghW, const float* __restrict__ ghb,
    float* __restrict__ h0, float* __restrict__ h1,
    float* __restrict__ m0, float* __restrict__ m1,
    float* __restrict__ s0, float* __restrict__ s1)
{
    int t = blockIdx.x * 256 + threadIdx.x;
    if (t >= NBATCH * NN) return;
    size_t off = (size_t)t * Hd;

    float h1v[Hd], m0v[Hd], m1v[Hd];
#pragma unroll
    for (int i = 0; i < Hd; ++i) {
        h1v[i] = h1[off + i];
        float m0n = m0[off + i] + s0[off + i];
        m0v[i] = m0n;
        m1v[i] = m0n + s1[off + i];
        m0[off + i] = m0n;
        m1[off + i] = m1v[i];
        s0[off + i] = 0.0f;
        s1[off + i] = 0.0f;
    }

    float a[15];
#pragma unroll
    for (int i = 0; i < Hd; ++i) { a[i] = h1v[i]; a[5 + i] = m0v[i]; a[10 + i] = m1v[i]; }

    float z[Hd], r[Hd];
#pragma unroll
    for (int i = 0; i < Hd; ++i) {
        float tz = gzb[i], tr = grb[i];
#pragma unroll
        for (int j = 0; j < 15; ++j) {
            tz = fmaf(a[j], gzW[j * Hd + i], tz);
            tr = fmaf(a[j], grW[j * Hd + i], tr);
        }
        z[i] = sigmoidf_(tz);
        r[i] = sigmoidf_(tr);
    }

    float joined[15];
#pragma unroll
    for (int i = 0; i < Hd; ++i) { joined[i] = r[i] * h1v[i]; joined[5 + i] = m0v[i]; joined[10 + i] = m1v[i]; }

#pragma unroll
    for (int i = 0; i < Hd; ++i) {
        float th = ghb[i];
#pragma unroll
        for (int j = 0; j < 15; ++j) th = fmaf(joined[j], ghW[j * Hd + i], th);
        float hh = tanhf(th);
        float hn = (1.0f - z[i]) * h1v[i] + z[i] * hh;
        h0[off + i] = h1v[i];
        h1[off + i] = hn;
    }
}

// ---------------------------------------------------------------------------
// output MLP: [h1, b] (6) -> 64 relu -> 64 relu -> 1 sigmoid
// ---------------------------------------------------------------------------
__global__ void out_kernel(
    const float* __restrict__ bnode, const float* __restrict__ h1,
    const float* __restrict__ oW1, const float* __restrict__ ob1,
    const float* __restrict__ oW2T, const float* __restrict__ ob2,
    const float* __restrict__ oW3, const float* __restrict__ ob3,
    float* __restrict__ out)
{
    int t = blockIdx.x * 256 + threadIdx.x;
    if (t >= NBATCH * NN) return;

    float x[6];
#pragma unroll
    for (int i = 0; i < Hd; ++i) x[i] = h1[(size_t)t * Hd + i];
    x[5] = bnode[t];

    float a1[64];
#pragma unroll
    for (int k = 0; k < 64; ++k) {
        float v = ob1[k];
#pragma unroll
        for (int j = 0; j < 6; ++j) v = fmaf(x[j], oW1[j * 64 + k], v);
        a1[k] = fmaxf(v, 0.0f);
    }

    float acc = ob3[0];
#pragma unroll 1
    for (int q = 0; q < 64; ++q) {
        float v = ob2[q];
        const float* wc = oW2T + q * 64;
#pragma unroll
        for (int j = 0; j < 64; ++j) v = fmaf(a1[j], wc[j], v);
        v = fmaxf(v, 0.0f);
        acc = fmaf(v, oW3[q], acc);
    }
    out[t] = sigmoidf_(acc);
}

// ---------------------------------------------------------------------------
extern "C" void kernel_launch(void* const* d_in, const int* in_sizes, int n_in,
                              void* d_out, int out_size, void* d_ws, size_t ws_size,
                              hipStream_t stream) {
    const float* Jm    = (const float*)d_in[0];
    const float* bnode = (const float*)d_in[1];
    const int*   iin   = (const int*)d_in[2];
    const int*   iout  = (const int*)d_in[3];
    const float* mW1 = (const float*)d_in[4];
    const float* mb1 = (const float*)d_in[5];
    const float* mW2 = (const float*)d_in[6];
    const float* mb2 = (const float*)d_in[7];
    const float* mW3 = (const float*)d_in[8];
    const float* mb3 = (const float*)d_in[9];
    const float* gzW = (const float*)d_in[10];
    const float* gzb = (const float*)d_in[11];
    const float* grW = (const float*)d_in[12];
    const float* grb = (const float*)d_in[13];
    const float* ghW = (const float*)d_in[14];
    const float* ghb = (const float*)d_in[15];
    const float* oW1 = (const float*)d_in[16];
    const float* ob1 = (const float*)d_in[17];
    const float* oW2 = (const float*)d_in[18];
    const float* ob2 = (const float*)d_in[19];
    const float* oW3 = (const float*)d_in[20];
    const float* ob3 = (const float*)d_in[21];

    float* ws = (float*)d_ws;
    float* h0 = ws;
    float* h1 = ws + (size_t)BNH;
    float* m0 = ws + (size_t)2 * BNH;
    float* m1 = ws + (size_t)3 * BNH;
    float* s0 = ws + (size_t)4 * BNH;
    float* s1 = ws + (size_t)5 * BNH;
    float* W2T  = ws + (size_t)6 * BNH;
    float* oW2T = W2T + 4096;

    // zero all state (h0,h1,m0,m1,s0,s1)
    hipMemsetAsync(d_ws, 0, (size_t)6 * BNH * sizeof(float), stream);

    transpose64<<<16, 256, 0, stream>>>(mW2, W2T);
    transpose64<<<16, 256, 0, stream>>>(oW2, oW2T);

    dim3 mgrid(EE / 256, NBATCH);
    int ngrid = (NBATCH * NN + 255) / 256;

    for (int s = 0; s < 10; ++s) {
        msg_kernel<<<mgrid, 256, 0, stream>>>(Jm, bnode, iin, iout,
                                              mW1, mb1, W2T, mb2, mW3, mb3,
                                              h0, h1, s0, s1);
        node_kernel<<<ngrid, 256, 0, stream>>>(gzW, gzb, grW, grb, ghW, ghb,
                                               h0, h1, m0, m1, s0, s1);
    }

    out_kernel<<<ngrid, 256, 0, stream>>>(bnode, h1,
                                          oW1, ob1, oW2T, ob2, oW3, ob3,
                                          (float*)d_out);
}

// Round 2
// 7661.217 us; speedup vs baseline: 1.0024x; 1.0024x over previous
//
#include <hip/hip_runtime.h>
#include <math.h>

#define Hd 5
#define NN 20000
#define EE 320000
#define NBATCH 4
#define BNH (NBATCH * NN * Hd) /* 400000 */

__device__ __forceinline__ float sigmoidf_(float v) {
    return 1.0f / (1.0f + expf(-v));
}

// ---------------------------------------------------------------------------
// per-edge message kernel: computes me0 (from h0) and me1 (from h1),
// atomically accumulates into s0 / s1 at index_out.
// Layer-2 in accumulator form: acc[q] += a1_j * W2[j][q] — no a1[64] array,
// no spill, independent FMA chains, row-major W2 (uniform 256B s_loads).
// grid: (EE/256, NBATCH)
// ---------------------------------------------------------------------------
__global__ void __launch_bounds__(256) msg_kernel(
    const float* __restrict__ Jm, const float* __restrict__ bnode,
    const int* __restrict__ iin, const int* __restrict__ iout,
    const float* __restrict__ W1, const float* __restrict__ b1,
    const float* __restrict__ W2, const float* __restrict__ b2,
    const float* __restrict__ W3, const float* __restrict__ b3,
    const float* __restrict__ h0, const float* __restrict__ h1,
    float* __restrict__ s0, float* __restrict__ s1)
{
    int e = blockIdx.x * 256 + threadIdx.x;
    int bb = blockIdx.y;
    int io = iout[e];
    int ii = iin[e];
    float bin  = bnode[bb * NN + ii];
    float bout = bnode[bb * NN + io];
    float jm   = Jm[(size_t)bb * EE + e];
    size_t hoff = ((size_t)bb * NN + io) * Hd;

    float me[2][Hd];

#pragma unroll
    for (int ev = 0; ev < 2; ++ev) {
        const float* __restrict__ h = ev ? h1 : h0;
        float hx[Hd];
#pragma unroll
        for (int i = 0; i < Hd; ++i) hx[i] = h[hoff + i];

        // layer 2 accumulators, init with bias
        float acc[64];
#pragma unroll
        for (int q = 0; q < 64; ++q) acc[q] = b2[q];

#pragma unroll 2
        for (int j = 0; j < 64; ++j) {
            // layer 1, neuron j (W1 is [9][64] row-major; column j strided)
            float t = b1[j];
            t = fmaf(hx[0], W1[0 * 64 + j], t);
            t = fmaf(hx[1], W1[1 * 64 + j], t);
            t = fmaf(hx[2], W1[2 * 64 + j], t);
            t = fmaf(hx[3], W1[3 * 64 + j], t);
            t = fmaf(hx[4], W1[4 * 64 + j], t);
            t = fmaf(bin,   W1[5 * 64 + j], t);
            t = fmaf(bout,  W1[6 * 64 + j], t);
            t = fmaf(jm,    W1[7 * 64 + j], t);
            t = fmaf(-jm,   W1[8 * 64 + j], t);
            t = fmaxf(t, 0.0f);
            // layer 2: rank-1 update into acc (W2 row j contiguous, uniform)
            const float* __restrict__ w2r = W2 + j * 64;
#pragma unroll
            for (int q = 0; q < 64; ++q) acc[q] = fmaf(t, w2r[q], acc[q]);
        }

        // layer 3: relu(acc) @ W3 + b3
        float m[Hd];
#pragma unroll
        for (int i = 0; i < Hd; ++i) m[i] = b3[i];
#pragma unroll 4
        for (int q = 0; q < 64; ++q) {
            float v = fmaxf(acc[q], 0.0f);
#pragma unroll
            for (int i = 0; i < Hd; ++i) m[i] = fmaf(v, W3[q * Hd + i], m[i]);
        }
#pragma unroll
        for (int i = 0; i < Hd; ++i) me[ev][i] = m[i];
    }

#pragma unroll
    for (int i = 0; i < Hd; ++i) atomicAdd(&s0[hoff + i], me[0][i]);
#pragma unroll
    for (int i = 0; i < Hd; ++i) atomicAdd(&s1[hoff + i], me[1][i]);
}

// ---------------------------------------------------------------------------
// per-node GRU update.
// m0 += s0 ; m1 = m0_new + s1 (m0 persists across steps, m1 rebuilt)
// a = [h1, m0, m1]; z = sig(a@gzW+gzb); r = sig(a@grW+grb)
// h_hat = tanh([r*h1, m0, m1]@ghW+ghb); h_new = (1-z)*h1 + z*h_hat
// h0 <- h1 ; h1 <- h_new ; s0,s1 <- 0 (for next step)
// ---------------------------------------------------------------------------
__global__ void node_kernel(
    const float* __restrict__ gzW, const float* __restrict__ gzb,
    const float* __restrict__ grW, const float* __restrict__ grb,
    const float* __restrict__ ghW, const float* __restrict__ ghb,
    float* __restrict__ h0, float* __restrict__ h1,
    float* __restrict__ m0, float* __restrict__ m1,
    float* __restrict__ s0, float* __restrict__ s1)
{
    int t = blockIdx.x * 256 + threadIdx.x;
    if (t >= NBATCH * NN) return;
    size_t off = (size_t)t * Hd;

    float h1v[Hd], m0v[Hd], m1v[Hd];
#pragma unroll
    for (int i = 0; i < Hd; ++i) {
        h1v[i] = h1[off + i];
        float m0n = m0[off + i] + s0[off + i];
        m0v[i] = m0n;
        m1v[i] = m0n + s1[off + i];
        m0[off + i] = m0n;
        m1[off + i] = m1v[i];
        s0[off + i] = 0.0f;
        s1[off + i] = 0.0f;
    }

    float a[15];
#pragma unroll
    for (int i = 0; i < Hd; ++i) { a[i] = h1v[i]; a[5 + i] = m0v[i]; a[10 + i] = m1v[i]; }

    float z[Hd], r[Hd];
#pragma unroll
    for (int i = 0; i < Hd; ++i) {
        float tz = gzb[i], tr = grb[i];
#pragma unroll
        for (int j = 0; j < 15; ++j) {
            tz = fmaf(a[j], gzW[j * Hd + i], tz);
            tr = fmaf(a[j], grW[j * Hd + i], tr);
        }
        z[i] = sigmoidf_(tz);
        r[i] = sigmoidf_(tr);
    }

    float joined[15];
#pragma unroll
    for (int i = 0; i < Hd; ++i) { joined[i] = r[i] * h1v[i]; joined[5 + i] = m0v[i]; joined[10 + i] = m1v[i]; }

#pragma unroll
    for (int i = 0; i < Hd; ++i) {
        float th = ghb[i];
#pragma unroll
        for (int j = 0; j < 15; ++j) th = fmaf(joined[j], ghW[j * Hd + i], th);
        float hh = tanhf(th);
        float hn = (1.0f - z[i]) * h1v[i] + z[i] * hh;
        h0[off + i] = h1v[i];
        h1[off + i] = hn;
    }
}

// ---------------------------------------------------------------------------
// output MLP: [h1, b] (6) -> 64 relu -> 64 relu -> 1 sigmoid
// same accumulator restructure; row-major oW2 directly.
// ---------------------------------------------------------------------------
__global__ void __launch_bounds__(256) out_kernel(
    const float* __restrict__ bnode, const float* __restrict__ h1,
    const float* __restrict__ oW1, const float* __restrict__ ob1,
    const float* __restrict__ oW2, const float* __restrict__ ob2,
    const float* __restrict__ oW3, const float* __restrict__ ob3,
    float* __restrict__ out)
{
    int t = blockIdx.x * 256 + threadIdx.x;
    if (t >= NBATCH * NN) return;

    float x[6];
#pragma unroll
    for (int i = 0; i < Hd; ++i) x[i] = h1[(size_t)t * Hd + i];
    x[5] = bnode[t];

    float acc[64];
#pragma unroll
    for (int q = 0; q < 64; ++q) acc[q] = ob2[q];

#pragma unroll 2
    for (int j = 0; j < 64; ++j) {
        float v = ob1[j];
#pragma unroll
        for (int f = 0; f < 6; ++f) v = fmaf(x[f], oW1[f * 64 + j], v);
        v = fmaxf(v, 0.0f);
        const float* __restrict__ w2r = oW2 + j * 64;
#pragma unroll
        for (int q = 0; q < 64; ++q) acc[q] = fmaf(v, w2r[q], acc[q]);
    }

    float o = ob3[0];
#pragma unroll 4
    for (int q = 0; q < 64; ++q) o = fmaf(fmaxf(acc[q], 0.0f), oW3[q], o);
    out[t] = sigmoidf_(o);
}

// ---------------------------------------------------------------------------
extern "C" void kernel_launch(void* const* d_in, const int* in_sizes, int n_in,
                              void* d_out, int out_size, void* d_ws, size_t ws_size,
                              hipStream_t stream) {
    const float* Jm    = (const float*)d_in[0];
    const float* bnode = (const float*)d_in[1];
    const int*   iin   = (const int*)d_in[2];
    const int*   iout  = (const int*)d_in[3];
    const float* mW1 = (const float*)d_in[4];
    const float* mb1 = (const float*)d_in[5];
    const float* mW2 = (const float*)d_in[6];
    const float* mb2 = (const float*)d_in[7];
    const float* mW3 = (const float*)d_in[8];
    const float* mb3 = (const float*)d_in[9];
    const float* gzW = (const float*)d_in[10];
    const float* gzb = (const float*)d_in[11];
    const float* grW = (const float*)d_in[12];
    const float* grb = (const float*)d_in[13];
    const float* ghW = (const float*)d_in[14];
    const float* ghb = (const float*)d_in[15];
    const float* oW1 = (const float*)d_in[16];
    const float* ob1 = (const float*)d_in[17];
    const float* oW2 = (const float*)d_in[18];
    const float* ob2 = (const float*)d_in[19];
    const float* oW3 = (const float*)d_in[20];
    const float* ob3 = (const float*)d_in[21];

    float* ws = (float*)d_ws;
    float* h0 = ws;
    float* h1 = ws + (size_t)BNH;
    float* m0 = ws + (size_t)2 * BNH;
    float* m1 = ws + (size_t)3 * BNH;
    float* s0 = ws + (size_t)4 * BNH;
    float* s1 = ws + (size_t)5 * BNH;

    // zero all state (h0,h1,m0,m1,s0,s1)
    hipMemsetAsync(d_ws, 0, (size_t)6 * BNH * sizeof(float), stream);

    dim3 mgrid(EE / 256, NBATCH);
    int ngrid = (NBATCH * NN + 255) / 256;

    for (int s = 0; s < 10; ++s) {
        msg_kernel<<<mgrid, 256, 0, stream>>>(Jm, bnode, iin, iout,
                                              mW1, mb1, mW2, mb2, mW3, mb3,
                                              h0, h1, s0, s1);
        node_kernel<<<ngrid, 256, 0, stream>>>(gzW, gzb, grW, grb, ghW, ghb,
                                               h0, h1, m0, m1, s0, s1);
    }

    out_kernel<<<ngrid, 256, 0, stream>>>(bnode, h1,
                                          oW1, ob1, oW2, ob2, oW3, ob3,
                                          (float*)d_out);
}

// Round 3
// 3955.499 us; speedup vs baseline: 1.9415x; 1.9369x over previous
//
#include <hip/hip_runtime.h>
#include <math.h>

#define Hd 5
#define NN 20000
#define EE 320000
#define NBATCH 4
#define BNH (NBATCH * NN * Hd) /* 400000 */

__device__ __forceinline__ float sigmoidf_(float v) {
    return 1.0f / (1.0f + expf(-v));
}

// ---------------------------------------------------------------------------
// per-edge message kernel: computes me = message(h1[index_out]) and
// atomically accumulates into sCur. (S0 of next step == S1 of this step,
// so only ONE MLP eval per edge per step is needed.)
// __launch_bounds__(256,1): allow up to 512 VGPRs so acc[64] stays in
// registers (round-2 failure: compiler demoted acc to scratch at VGPR=44,
// 1.6GB/dispatch scratch write-through).
// grid: (EE/256, NBATCH)
// ---------------------------------------------------------------------------
__global__ void __launch_bounds__(256, 1) msg_kernel(
    const float* __restrict__ Jm, const float* __restrict__ bnode,
    const int* __restrict__ iin, const int* __restrict__ iout,
    const float* __restrict__ W1, const float* __restrict__ b1,
    const float* __restrict__ W2, const float* __restrict__ b2,
    const float* __restrict__ W3, const float* __restrict__ b3,
    const float* __restrict__ h1,
    float* __restrict__ sCur)
{
    int e = blockIdx.x * 256 + threadIdx.x;
    int bb = blockIdx.y;
    int io = iout[e];
    int ii = iin[e];
    float bin  = bnode[bb * NN + ii];
    float bout = bnode[bb * NN + io];
    float jm   = Jm[(size_t)bb * EE + e];
    size_t hoff = ((size_t)bb * NN + io) * Hd;

    float hx[Hd];
#pragma unroll
    for (int i = 0; i < Hd; ++i) hx[i] = h1[hoff + i];

    // layer 2 accumulators, init with bias
    float acc[64];
#pragma unroll
    for (int q = 0; q < 64; ++q) acc[q] = b2[q];

#pragma unroll 2
    for (int j = 0; j < 64; ++j) {
        // layer 1, neuron j (W1 is [9][64] row-major; column j strided)
        float t = b1[j];
        t = fmaf(hx[0], W1[0 * 64 + j], t);
        t = fmaf(hx[1], W1[1 * 64 + j], t);
        t = fmaf(hx[2], W1[2 * 64 + j], t);
        t = fmaf(hx[3], W1[3 * 64 + j], t);
        t = fmaf(hx[4], W1[4 * 64 + j], t);
        t = fmaf(bin,   W1[5 * 64 + j], t);
        t = fmaf(bout,  W1[6 * 64 + j], t);
        t = fmaf(jm,    W1[7 * 64 + j], t);
        t = fmaf(-jm,   W1[8 * 64 + j], t);
        t = fmaxf(t, 0.0f);
        // layer 2: rank-1 update into acc (W2 row j contiguous, uniform s_load)
        const float* __restrict__ w2r = W2 + j * 64;
#pragma unroll
        for (int q = 0; q < 64; ++q) acc[q] = fmaf(t, w2r[q], acc[q]);
    }

    // layer 3: relu(acc) @ W3 + b3
    float m[Hd];
#pragma unroll
    for (int i = 0; i < Hd; ++i) m[i] = b3[i];
#pragma unroll 4
    for (int q = 0; q < 64; ++q) {
        float v = fmaxf(acc[q], 0.0f);
#pragma unroll
        for (int i = 0; i < Hd; ++i) m[i] = fmaf(v, W3[q * Hd + i], m[i]);
    }

#pragma unroll
    for (int i = 0; i < Hd; ++i) atomicAdd(&sCur[hoff + i], m[i]);
}

// ---------------------------------------------------------------------------
// per-node GRU update.
// m0 += s0 ; m1 = m0_new + s1 (m0 persists, m1 local)
// a = [h1, m0, m1]; z = sig(a@gzW+gzb); r = sig(a@grW+grb)
// h_hat = tanh([r*h1, m0, m1]@ghW+ghb); h1 <- (1-z)*h1 + z*h_hat
// zeroPrev: zero s0buf after reading (it becomes next step's sCur).
// ---------------------------------------------------------------------------
__global__ void node_kernel(
    const float* __restrict__ gzW, const float* __restrict__ gzb,
    const float* __restrict__ grW, const float* __restrict__ grb,
    const float* __restrict__ ghW, const float* __restrict__ ghb,
    float* __restrict__ h1, float* __restrict__ m0,
    float* __restrict__ s0buf, const float* __restrict__ s1buf,
    int zeroPrev)
{
    int t = blockIdx.x * 256 + threadIdx.x;
    if (t >= NBATCH * NN) return;
    size_t off = (size_t)t * Hd;

    float h1v[Hd], m0v[Hd], m1v[Hd];
#pragma unroll
    for (int i = 0; i < Hd; ++i) {
        h1v[i] = h1[off + i];
        float m0n = m0[off + i] + s0buf[off + i];
        m0v[i] = m0n;
        m1v[i] = m0n + s1buf[off + i];
        m0[off + i] = m0n;
        if (zeroPrev) s0buf[off + i] = 0.0f;
    }

    float a[15];
#pragma unroll
    for (int i = 0; i < Hd; ++i) { a[i] = h1v[i]; a[5 + i] = m0v[i]; a[10 + i] = m1v[i]; }

    float z[Hd], r[Hd];
#pragma unroll
    for (int i = 0; i < Hd; ++i) {
        float tz = gzb[i], tr = grb[i];
#pragma unroll
        for (int j = 0; j < 15; ++j) {
            tz = fmaf(a[j], gzW[j * Hd + i], tz);
            tr = fmaf(a[j], grW[j * Hd + i], tr);
        }
        z[i] = sigmoidf_(tz);
        r[i] = sigmoidf_(tr);
    }

    float joined[15];
#pragma unroll
    for (int i = 0; i < Hd; ++i) { joined[i] = r[i] * h1v[i]; joined[5 + i] = m0v[i]; joined[10 + i] = m1v[i]; }

#pragma unroll
    for (int i = 0; i < Hd; ++i) {
        float th = ghb[i];
#pragma unroll
        for (int j = 0; j < 15; ++j) th = fmaf(joined[j], ghW[j * Hd + i], th);
        float hh = tanhf(th);
        h1[off + i] = (1.0f - z[i]) * h1v[i] + z[i] * hh;
    }
}

// ---------------------------------------------------------------------------
// output MLP: [h1, b] (6) -> 64 relu -> 64 relu -> 1 sigmoid
// ---------------------------------------------------------------------------
__global__ void __launch_bounds__(256, 1) out_kernel(
    const float* __restrict__ bnode, const float* __restrict__ h1,
    const float* __restrict__ oW1, const float* __restrict__ ob1,
    const float* __restrict__ oW2, const float* __restrict__ ob2,
    const float* __restrict__ oW3, const float* __restrict__ ob3,
    float* __restrict__ out)
{
    int t = blockIdx.x * 256 + threadIdx.x;
    if (t >= NBATCH * NN) return;

    float x[6];
#pragma unroll
    for (int i = 0; i < Hd; ++i) x[i] = h1[(size_t)t * Hd + i];
    x[5] = bnode[t];

    float acc[64];
#pragma unroll
    for (int q = 0; q < 64; ++q) acc[q] = ob2[q];

#pragma unroll 2
    for (int j = 0; j < 64; ++j) {
        float v = ob1[j];
#pragma unroll
        for (int f = 0; f < 6; ++f) v = fmaf(x[f], oW1[f * 64 + j], v);
        v = fmaxf(v, 0.0f);
        const float* __restrict__ w2r = oW2 + j * 64;
#pragma unroll
        for (int q = 0; q < 64; ++q) acc[q] = fmaf(v, w2r[q], acc[q]);
    }

    float o = ob3[0];
#pragma unroll 4
    for (int q = 0; q < 64; ++q) o = fmaf(fmaxf(acc[q], 0.0f), oW3[q], o);
    out[t] = sigmoidf_(o);
}

// ---------------------------------------------------------------------------
extern "C" void kernel_launch(void* const* d_in, const int* in_sizes, int n_in,
                              void* d_out, int out_size, void* d_ws, size_t ws_size,
                              hipStream_t stream) {
    const float* Jm    = (const float*)d_in[0];
    const float* bnode = (const float*)d_in[1];
    const int*   iin   = (const int*)d_in[2];
    const int*   iout  = (const int*)d_in[3];
    const float* mW1 = (const float*)d_in[4];
    const float* mb1 = (const float*)d_in[5];
    const float* mW2 = (const float*)d_in[6];
    const float* mb2 = (const float*)d_in[7];
    const float* mW3 = (const float*)d_in[8];
    const float* mb3 = (const float*)d_in[9];
    const float* gzW = (const float*)d_in[10];
    const float* gzb = (const float*)d_in[11];
    const float* grW = (const float*)d_in[12];
    const float* grb = (const float*)d_in[13];
    const float* ghW = (const float*)d_in[14];
    const float* ghb = (const float*)d_in[15];
    const float* oW1 = (const float*)d_in[16];
    const float* ob1 = (const float*)d_in[17];
    const float* oW2 = (const float*)d_in[18];
    const float* ob2 = (const float*)d_in[19];
    const float* oW3 = (const float*)d_in[20];
    const float* ob3 = (const float*)d_in[21];

    float* ws = (float*)d_ws;
    float* h1 = ws;
    float* m0 = ws + (size_t)BNH;
    float* sA = ws + (size_t)2 * BNH;
    float* sB = ws + (size_t)3 * BNH;

    // zero all state (h1, m0, sA, sB)
    hipMemsetAsync(d_ws, 0, (size_t)4 * BNH * sizeof(float), stream);

    dim3 mgrid(EE / 256, NBATCH);
    int ngrid = (NBATCH * NN + 255) / 256;

    float* buf[2] = { sA, sB };
    for (int s = 0; s < 10; ++s) {
        float* sCur  = buf[s & 1];
        float* sPrev = (s == 0) ? sCur : buf[(s + 1) & 1];
        msg_kernel<<<mgrid, 256, 0, stream>>>(Jm, bnode, iin, iout,
                                              mW1, mb1, mW2, mb2, mW3, mb3,
                                              h1, sCur);
        // s0 = sPrev (== S1 of previous step), s1 = sCur.
        // Zero sPrev after reading (it becomes sCur two steps later),
        // except at step 0 where sPrev==sCur holds live data.
        node_kernel<<<ngrid, 256, 0, stream>>>(gzW, gzb, grW, grb, ghW, ghb,
                                               h1, m0, sPrev, sCur,
                                               (s == 0) ? 0 : 1);
    }

    out_kernel<<<ngrid, 256, 0, stream>>>(bnode, h1,
                                          oW1, ob1, oW2, ob2, oW3, ob3,
                                          (float*)d_out);
}

// Round 4
// 3628.480 us; speedup vs baseline: 2.1165x; 1.0901x over previous
//
#include <hip/hip_runtime.h>
#include <math.h>

#define Hd 5
#define NN 20000
#define EE 320000
#define NBATCH 4
#define BNH (NBATCH * NN * Hd) /* 400000 */

__device__ __forceinline__ float sigmoidf_(float v) {
    return 1.0f / (1.0f + expf(-v));
}

// ---------------------------------------------------------------------------
// per-edge message kernel: computes me = message(h1[index_out]) and
// atomically accumulates into sCur. (S0 of next step == S1 of this step,
// so only ONE MLP eval per edge per step is needed.)
// CRITICAL: every loop touching acc[] is FULLY unrolled — any runtime index
// into a local array demotes the whole array to scratch (round-3 failure:
// "#pragma unroll 4" left q runtime -> acc in scratch -> 1 GB/dispatch HBM).
// grid: (EE/256, NBATCH)
// ---------------------------------------------------------------------------
__global__ void __launch_bounds__(256, 1) msg_kernel(
    const float* __restrict__ Jm, const float* __restrict__ bnode,
    const int* __restrict__ iin, const int* __restrict__ iout,
    const float* __restrict__ W1, const float* __restrict__ b1,
    const float* __restrict__ W2, const float* __restrict__ b2,
    const float* __restrict__ W3, const float* __restrict__ b3,
    const float* __restrict__ h1,
    float* __restrict__ sCur)
{
    int e = blockIdx.x * 256 + threadIdx.x;
    int bb = blockIdx.y;
    int io = iout[e];
    int ii = iin[e];
    float bin  = bnode[bb * NN + ii];
    float bout = bnode[bb * NN + io];
    float jm   = Jm[(size_t)bb * EE + e];
    size_t hoff = ((size_t)bb * NN + io) * Hd;

    float hx[Hd];
#pragma unroll
    for (int i = 0; i < Hd; ++i) hx[i] = h1[hoff + i];

    // layer 2 accumulators, init with bias (all-static indexing)
    float acc[64];
#pragma unroll
    for (int q = 0; q < 64; ++q) acc[q] = b2[q];

#pragma unroll 2
    for (int j = 0; j < 64; ++j) {
        // layer 1, neuron j (W1 is [9][64] row-major; column j strided)
        float t = b1[j];
        t = fmaf(hx[0], W1[0 * 64 + j], t);
        t = fmaf(hx[1], W1[1 * 64 + j], t);
        t = fmaf(hx[2], W1[2 * 64 + j], t);
        t = fmaf(hx[3], W1[3 * 64 + j], t);
        t = fmaf(hx[4], W1[4 * 64 + j], t);
        t = fmaf(bin,   W1[5 * 64 + j], t);
        t = fmaf(bout,  W1[6 * 64 + j], t);
        t = fmaf(jm,    W1[7 * 64 + j], t);
        t = fmaf(-jm,   W1[8 * 64 + j], t);
        t = fmaxf(t, 0.0f);
        // layer 2: rank-1 update into acc (W2 row j contiguous, uniform s_load)
        const float* __restrict__ w2r = W2 + j * 64;
#pragma unroll
        for (int q = 0; q < 64; ++q) acc[q] = fmaf(t, w2r[q], acc[q]);
    }

    // layer 3: relu(acc) @ W3 + b3 — FULLY unrolled (static acc indices)
    float m[Hd];
#pragma unroll
    for (int i = 0; i < Hd; ++i) m[i] = b3[i];
#pragma unroll
    for (int q = 0; q < 64; ++q) {
        float v = fmaxf(acc[q], 0.0f);
#pragma unroll
        for (int i = 0; i < Hd; ++i) m[i] = fmaf(v, W3[q * Hd + i], m[i]);
    }

#pragma unroll
    for (int i = 0; i < Hd; ++i) atomicAdd(&sCur[hoff + i], m[i]);
}

// ---------------------------------------------------------------------------
// per-node GRU update.
// m0 += s0 ; m1 = m0_new + s1 (m0 persists, m1 local)
// a = [h1, m0, m1]; z = sig(a@gzW+gzb); r = sig(a@grW+grb)
// h_hat = tanh([r*h1, m0, m1]@ghW+ghb); h1 <- (1-z)*h1 + z*h_hat
// zeroPrev: zero s0buf after reading (it becomes next step's sCur).
// ---------------------------------------------------------------------------
__global__ void node_kernel(
    const float* __restrict__ gzW, const float* __restrict__ gzb,
    const float* __restrict__ grW, const float* __restrict__ grb,
    const float* __restrict__ ghW, const float* __restrict__ ghb,
    float* __restrict__ h1, float* __restrict__ m0,
    float* __restrict__ s0buf, const float* __restrict__ s1buf,
    int zeroPrev)
{
    int t = blockIdx.x * 256 + threadIdx.x;
    if (t >= NBATCH * NN) return;
    size_t off = (size_t)t * Hd;

    float h1v[Hd], m0v[Hd], m1v[Hd];
#pragma unroll
    for (int i = 0; i < Hd; ++i) {
        h1v[i] = h1[off + i];
        float m0n = m0[off + i] + s0buf[off + i];
        m0v[i] = m0n;
        m1v[i] = m0n + s1buf[off + i];
        m0[off + i] = m0n;
        if (zeroPrev) s0buf[off + i] = 0.0f;
    }

    float a[15];
#pragma unroll
    for (int i = 0; i < Hd; ++i) { a[i] = h1v[i]; a[5 + i] = m0v[i]; a[10 + i] = m1v[i]; }

    float z[Hd], r[Hd];
#pragma unroll
    for (int i = 0; i < Hd; ++i) {
        float tz = gzb[i], tr = grb[i];
#pragma unroll
        for (int j = 0; j < 15; ++j) {
            tz = fmaf(a[j], gzW[j * Hd + i], tz);
            tr = fmaf(a[j], grW[j * Hd + i], tr);
        }
        z[i] = sigmoidf_(tz);
        r[i] = sigmoidf_(tr);
    }

    float joined[15];
#pragma unroll
    for (int i = 0; i < Hd; ++i) { joined[i] = r[i] * h1v[i]; joined[5 + i] = m0v[i]; joined[10 + i] = m1v[i]; }

#pragma unroll
    for (int i = 0; i < Hd; ++i) {
        float th = ghb[i];
#pragma unroll
        for (int j = 0; j < 15; ++j) th = fmaf(joined[j], ghW[j * Hd + i], th);
        float hh = tanhf(th);
        h1[off + i] = (1.0f - z[i]) * h1v[i] + z[i] * hh;
    }
}

// ---------------------------------------------------------------------------
// output MLP: [h1, b] (6) -> 64 relu -> 64 relu -> 1 sigmoid
// final reduce fully unrolled (static acc indices).
// ---------------------------------------------------------------------------
__global__ void __launch_bounds__(256, 1) out_kernel(
    const float* __restrict__ bnode, const float* __restrict__ h1,
    const float* __restrict__ oW1, const float* __restrict__ ob1,
    const float* __restrict__ oW2, const float* __restrict__ ob2,
    const float* __restrict__ oW3, const float* __restrict__ ob3,
    float* __restrict__ out)
{
    int t = blockIdx.x * 256 + threadIdx.x;
    if (t >= NBATCH * NN) return;

    float x[6];
#pragma unroll
    for (int i = 0; i < Hd; ++i) x[i] = h1[(size_t)t * Hd + i];
    x[5] = bnode[t];

    float acc[64];
#pragma unroll
    for (int q = 0; q < 64; ++q) acc[q] = ob2[q];

#pragma unroll 2
    for (int j = 0; j < 64; ++j) {
        float v = ob1[j];
#pragma unroll
        for (int f = 0; f < 6; ++f) v = fmaf(x[f], oW1[f * 64 + j], v);
        v = fmaxf(v, 0.0f);
        const float* __restrict__ w2r = oW2 + j * 64;
#pragma unroll
        for (int q = 0; q < 64; ++q) acc[q] = fmaf(v, w2r[q], acc[q]);
    }

    float o = ob3[0];
#pragma unroll
    for (int q = 0; q < 64; ++q) o = fmaf(fmaxf(acc[q], 0.0f), oW3[q], o);
    out[t] = sigmoidf_(o);
}

// ---------------------------------------------------------------------------
extern "C" void kernel_launch(void* const* d_in, const int* in_sizes, int n_in,
                              void* d_out, int out_size, void* d_ws, size_t ws_size,
                              hipStream_t stream) {
    const float* Jm    = (const float*)d_in[0];
    const float* bnode = (const float*)d_in[1];
    const int*   iin   = (const int*)d_in[2];
    const int*   iout  = (const int*)d_in[3];
    const float* mW1 = (const float*)d_in[4];
    const float* mb1 = (const float*)d_in[5];
    const float* mW2 = (const float*)d_in[6];
    const float* mb2 = (const float*)d_in[7];
    const float* mW3 = (const float*)d_in[8];
    const float* mb3 = (const float*)d_in[9];
    const float* gzW = (const float*)d_in[10];
    const float* gzb = (const float*)d_in[11];
    const float* grW = (const float*)d_in[12];
    const float* grb = (const float*)d_in[13];
    const float* ghW = (const float*)d_in[14];
    const float* ghb = (const float*)d_in[15];
    const float* oW1 = (const float*)d_in[16];
    const float* ob1 = (const float*)d_in[17];
    const float* oW2 = (const float*)d_in[18];
    const float* ob2 = (const float*)d_in[19];
    const float* oW3 = (const float*)d_in[20];
    const float* ob3 = (const float*)d_in[21];

    float* ws = (float*)d_ws;
    float* h1 = ws;
    float* m0 = ws + (size_t)BNH;
    float* sA = ws + (size_t)2 * BNH;
    float* sB = ws + (size_t)3 * BNH;

    // zero all state (h1, m0, sA, sB)
    hipMemsetAsync(d_ws, 0, (size_t)4 * BNH * sizeof(float), stream);

    dim3 mgrid(EE / 256, NBATCH);
    int ngrid = (NBATCH * NN + 255) / 256;

    float* buf[2] = { sA, sB };
    for (int s = 0; s < 10; ++s) {
        float* sCur  = buf[s & 1];
        float* sPrev = (s == 0) ? sCur : buf[(s + 1) & 1];
        msg_kernel<<<mgrid, 256, 0, stream>>>(Jm, bnode, iin, iout,
                                              mW1, mb1, mW2, mb2, mW3, mb3,
                                              h1, sCur);
        // s0 = sPrev (== S1 of previous step), s1 = sCur.
        // Zero sPrev after reading (it becomes sCur two steps later),
        // except at step 0 where sPrev==sCur holds live data.
        node_kernel<<<ngrid, 256, 0, stream>>>(gzW, gzb, grW, grb, ghW, ghb,
                                               h1, m0, sPrev, sCur,
                                               (s == 0) ? 0 : 1);
    }

    out_kernel<<<ngrid, 256, 0, stream>>>(bnode, h1,
                                          oW1, ob1, oW2, ob2, oW3, ob3,
                                          (float*)d_out);
}

// Round 5
// 1725.574 us; speedup vs baseline: 4.4505x; 2.1028x over previous
//
#include <hip/hip_runtime.h>
#include <math.h>

#define Hd 5
#define NN 20000
#define EE 320000
#define NBATCH 4
#define BNH (NBATCH * NN * Hd) /* 400000 */

__device__ __forceinline__ float sigmoidf_(float v) {
    return 1.0f / (1.0f + expf(-v));
}

// ===========================================================================
// one-time per-launch edge sort by index_out (counting sort, device-side)
// ===========================================================================
__global__ void k_hist(const int* __restrict__ iout, unsigned* __restrict__ cnt) {
    int t = blockIdx.x * 256 + threadIdx.x;
    atomicAdd(&cnt[iout[t]], 1u);
}

// single block, 256 threads; exclusive scan of cnt[20000] -> row_start
__global__ void k_scan(const unsigned* __restrict__ cnt, unsigned* __restrict__ row) {
    __shared__ unsigned part[256];
    int i = threadIdx.x;
    unsigned s = 0;
    if (i < 250) {
        for (int k = 0; k < 80; ++k) s += cnt[i * 80 + k];
    }
    part[i] = s;
    __syncthreads();
    // inclusive Hillis-Steele scan over part[256]
    for (int off = 1; off < 256; off <<= 1) {
        unsigned v = part[i];
        unsigned u = (i >= off) ? part[i - off] : 0u;
        __syncthreads();
        part[i] = v + u;
        __syncthreads();
    }
    unsigned run = (i == 0) ? 0u : part[i - 1];
    if (i < 250) {
        for (int k = 0; k < 80; ++k) {
            row[i * 80 + k] = run;
            run += cnt[i * 80 + k];
        }
    }
}

__global__ void k_scatter(const int* __restrict__ iout,
                          const unsigned* __restrict__ row,
                          unsigned* __restrict__ cur,
                          unsigned* __restrict__ perm) {
    int t = blockIdx.x * 256 + threadIdx.x;
    int io = iout[t];
    unsigned pos = row[io] + atomicAdd(&cur[io], 1u);
    perm[pos] = (unsigned)t;
}

// materialize sorted copies so the 10 step-kernels run fully coalesced
__global__ void k_mat(const unsigned* __restrict__ perm,
                      const int* __restrict__ iout, const int* __restrict__ iin,
                      const float* __restrict__ Jm,
                      int* __restrict__ sout, int* __restrict__ sin,
                      float* __restrict__ sJ) {
    int t = blockIdx.x * 256 + threadIdx.x;
    unsigned e = perm[t];
    sout[t] = iout[e];
    sin[t]  = iin[e];
#pragma unroll
    for (int b = 0; b < NBATCH; ++b)
        sJ[(size_t)b * EE + t] = Jm[(size_t)b * EE + e];
}

// ===========================================================================
// per-edge message kernel over SORTED edges + wave segmented reduction.
// Only segment-tail lanes issue atomics (~5/wave instead of 64).
// Layer 2 split into 2x32-output passes (acc[32]) to bound register live-set.
// grid: (EE/256, NBATCH)
// ===========================================================================
__global__ void __launch_bounds__(256, 1) msg_kernel(
    const float* __restrict__ sJ, const float* __restrict__ bnode,
    const int* __restrict__ sin, const int* __restrict__ sout,
    const float* __restrict__ W1, const float* __restrict__ b1,
    const float* __restrict__ W2, const float* __restrict__ b2,
    const float* __restrict__ W3, const float* __restrict__ b3,
    const float* __restrict__ h1,
    float* __restrict__ sCur)
{
    int t = blockIdx.x * 256 + threadIdx.x;
    int bb = blockIdx.y;
    int io = sout[t];
    int ii = sin[t];
    float bin  = bnode[bb * NN + ii];
    float bout = bnode[bb * NN + io];
    float jm   = sJ[(size_t)bb * EE + t];
    size_t hoff = ((size_t)bb * NN + io) * Hd;

    float hx[Hd];
#pragma unroll
    for (int i = 0; i < Hd; ++i) hx[i] = h1[hoff + i];

    float m[Hd];
#pragma unroll
    for (int i = 0; i < Hd; ++i) m[i] = b3[i];

#pragma unroll
    for (int half = 0; half < 2; ++half) {
        float acc[32];
#pragma unroll
        for (int q = 0; q < 32; ++q) acc[q] = b2[half * 32 + q];

#pragma unroll 2
        for (int j = 0; j < 64; ++j) {
            float v = b1[j];
            v = fmaf(hx[0], W1[0 * 64 + j], v);
            v = fmaf(hx[1], W1[1 * 64 + j], v);
            v = fmaf(hx[2], W1[2 * 64 + j], v);
            v = fmaf(hx[3], W1[3 * 64 + j], v);
            v = fmaf(hx[4], W1[4 * 64 + j], v);
            v = fmaf(bin,   W1[5 * 64 + j], v);
            v = fmaf(bout,  W1[6 * 64 + j], v);
            v = fmaf(jm,    W1[7 * 64 + j], v);
            v = fmaf(-jm,   W1[8 * 64 + j], v);
            v = fmaxf(v, 0.0f);
            const float* __restrict__ w2r = W2 + j * 64 + half * 32;
#pragma unroll
            for (int q = 0; q < 32; ++q) acc[q] = fmaf(v, w2r[q], acc[q]);
        }

#pragma unroll
        for (int q = 0; q < 32; ++q) {
            float v = fmaxf(acc[q], 0.0f);
#pragma unroll
            for (int i = 0; i < Hd; ++i)
                m[i] = fmaf(v, W3[(half * 32 + q) * Hd + i], m[i]);
        }
    }

    // ---- wave-level segmented sum over sorted keys (io) ----
    int lane = threadIdx.x & 63;
#pragma unroll
    for (int off = 1; off < 64; off <<= 1) {
        int ko = __shfl_up(io, off, 64);
        bool add = (lane >= off) && (ko == io);
#pragma unroll
        for (int i = 0; i < Hd; ++i) {
            float u = __shfl_up(m[i], off, 64);
            if (add) m[i] += u;
        }
    }
    int nk = __shfl_down(io, 1, 64);
    bool tail = (lane == 63) || (nk != io);
    if (tail) {
#pragma unroll
        for (int i = 0; i < Hd; ++i) atomicAdd(&sCur[hoff + i], m[i]);
    }
}

// ---------------------------------------------------------------------------
// per-node GRU update (unchanged, verified).
// ---------------------------------------------------------------------------
__global__ void node_kernel(
    const float* __restrict__ gzW, const float* __restrict__ gzb,
    const float* __restrict__ grW, const float* __restrict__ grb,
    const float* __restrict__ ghW, const float* __restrict__ ghb,
    float* __restrict__ h1, float* __restrict__ m0,
    float* __restrict__ s0buf, const float* __restrict__ s1buf,
    int zeroPrev)
{
    int t = blockIdx.x * 256 + threadIdx.x;
    if (t >= NBATCH * NN) return;
    size_t off = (size_t)t * Hd;

    float h1v[Hd], m0v[Hd], m1v[Hd];
#pragma unroll
    for (int i = 0; i < Hd; ++i) {
        h1v[i] = h1[off + i];
        float m0n = m0[off + i] + s0buf[off + i];
        m0v[i] = m0n;
        m1v[i] = m0n + s1buf[off + i];
        m0[off + i] = m0n;
        if (zeroPrev) s0buf[off + i] = 0.0f;
    }

    float a[15];
#pragma unroll
    for (int i = 0; i < Hd; ++i) { a[i] = h1v[i]; a[5 + i] = m0v[i]; a[10 + i] = m1v[i]; }

    float z[Hd], r[Hd];
#pragma unroll
    for (int i = 0; i < Hd; ++i) {
        float tz = gzb[i], tr = grb[i];
#pragma unroll
        for (int j = 0; j < 15; ++j) {
            tz = fmaf(a[j], gzW[j * Hd + i], tz);
            tr = fmaf(a[j], grW[j * Hd + i], tr);
        }
        z[i] = sigmoidf_(tz);
        r[i] = sigmoidf_(tr);
    }

    float joined[15];
#pragma unroll
    for (int i = 0; i < Hd; ++i) { joined[i] = r[i] * h1v[i]; joined[5 + i] = m0v[i]; joined[10 + i] = m1v[i]; }

#pragma unroll
    for (int i = 0; i < Hd; ++i) {
        float th = ghb[i];
#pragma unroll
        for (int j = 0; j < 15; ++j) th = fmaf(joined[j], ghW[j * Hd + i], th);
        float hh = tanhf(th);
        h1[off + i] = (1.0f - z[i]) * h1v[i] + z[i] * hh;
    }
}

// ---------------------------------------------------------------------------
// output MLP (unchanged, verified; runs once, ~4 us)
// ---------------------------------------------------------------------------
__global__ void __launch_bounds__(256, 1) out_kernel(
    const float* __restrict__ bnode, const float* __restrict__ h1,
    const float* __restrict__ oW1, const float* __restrict__ ob1,
    const float* __restrict__ oW2, const float* __restrict__ ob2,
    const float* __restrict__ oW3, const float* __restrict__ ob3,
    float* __restrict__ out)
{
    int t = blockIdx.x * 256 + threadIdx.x;
    if (t >= NBATCH * NN) return;

    float x[6];
#pragma unroll
    for (int i = 0; i < Hd; ++i) x[i] = h1[(size_t)t * Hd + i];
    x[5] = bnode[t];

    float acc[64];
#pragma unroll
    for (int q = 0; q < 64; ++q) acc[q] = ob2[q];

#pragma unroll 2
    for (int j = 0; j < 64; ++j) {
        float v = ob1[j];
#pragma unroll
        for (int f = 0; f < 6; ++f) v = fmaf(x[f], oW1[f * 64 + j], v);
        v = fmaxf(v, 0.0f);
        const float* __restrict__ w2r = oW2 + j * 64;
#pragma unroll
        for (int q = 0; q < 64; ++q) acc[q] = fmaf(v, w2r[q], acc[q]);
    }

    float o = ob3[0];
#pragma unroll
    for (int q = 0; q < 64; ++q) o = fmaf(fmaxf(acc[q], 0.0f), oW3[q], o);
    out[t] = sigmoidf_(o);
}

// ---------------------------------------------------------------------------
extern "C" void kernel_launch(void* const* d_in, const int* in_sizes, int n_in,
                              void* d_out, int out_size, void* d_ws, size_t ws_size,
                              hipStream_t stream) {
    const float* Jm    = (const float*)d_in[0];
    const float* bnode = (const float*)d_in[1];
    const int*   iin   = (const int*)d_in[2];
    const int*   iout  = (const int*)d_in[3];
    const float* mW1 = (const float*)d_in[4];
    const float* mb1 = (const float*)d_in[5];
    const float* mW2 = (const float*)d_in[6];
    const float* mb2 = (const float*)d_in[7];
    const float* mW3 = (const float*)d_in[8];
    const float* mb3 = (const float*)d_in[9];
    const float* gzW = (const float*)d_in[10];
    const float* gzb = (const float*)d_in[11];
    const float* grW = (const float*)d_in[12];
    const float* grb = (const float*)d_in[13];
    const float* ghW = (const float*)d_in[14];
    const float* ghb = (const float*)d_in[15];
    const float* oW1 = (const float*)d_in[16];
    const float* ob1 = (const float*)d_in[17];
    const float* oW2 = (const float*)d_in[18];
    const float* ob2 = (const float*)d_in[19];
    const float* oW3 = (const float*)d_in[20];
    const float* ob3 = (const float*)d_in[21];

    float* ws = (float*)d_ws;
    float* h1 = ws;
    float* m0 = ws + (size_t)BNH;
    float* sA = ws + (size_t)2 * BNH;
    float* sB = ws + (size_t)3 * BNH;
    unsigned* cnt  = (unsigned*)(ws + (size_t)4 * BNH);
    unsigned* cur  = cnt + NN;
    unsigned* row  = cur + NN;
    unsigned* perm = row + NN;
    int*      sout = (int*)(perm + EE);
    int*      sin  = sout + EE;
    float*    sJ   = (float*)(sin + EE);   // NBATCH*EE floats

    // zero h1, m0, sA, sB, cnt, cur (contiguous)
    hipMemsetAsync(d_ws, 0, ((size_t)4 * BNH + 2 * NN) * sizeof(float), stream);

    // one-time (per launch) counting sort of edges by index_out
    k_hist<<<EE / 256, 256, 0, stream>>>(iout, cnt);
    k_scan<<<1, 256, 0, stream>>>(cnt, row);
    k_scatter<<<EE / 256, 256, 0, stream>>>(iout, row, cur, perm);
    k_mat<<<EE / 256, 256, 0, stream>>>(perm, iout, iin, Jm, sout, sin, sJ);

    dim3 mgrid(EE / 256, NBATCH);
    int ngrid = (NBATCH * NN + 255) / 256;

    float* buf[2] = { sA, sB };
    for (int s = 0; s < 10; ++s) {
        float* sCur  = buf[s & 1];
        float* sPrev = (s == 0) ? sCur : buf[(s + 1) & 1];
        msg_kernel<<<mgrid, 256, 0, stream>>>(sJ, bnode, sin, sout,
                                              mW1, mb1, mW2, mb2, mW3, mb3,
                                              h1, sCur);
        node_kernel<<<ngrid, 256, 0, stream>>>(gzW, gzb, grW, grb, ghW, ghb,
                                               h1, m0, sPrev, sCur,
                                               (s == 0) ? 0 : 1);
    }

    out_kernel<<<ngrid, 256, 0, stream>>>(bnode, h1,
                                          oW1, ob1, oW2, ob2, oW3, ob3,
                                          (float*)d_out);
}

// Round 8
// 1197.430 us; speedup vs baseline: 6.4135x; 1.4411x over previous
//
#include <hip/hip_runtime.h>
#include <hip/hip_bf16.h>
#include <math.h>

#define Hd 5
#define NN 20000
#define EE 320000
#define NBATCH 4
#define BNH (NBATCH * NN * Hd) /* 400000 */

typedef __attribute__((ext_vector_type(8))) short short8;
typedef __attribute__((ext_vector_type(4))) float f32x4;

__device__ __forceinline__ float sigmoidf_(float v) {
    return 1.0f / (1.0f + expf(-v));
}

__device__ __forceinline__ unsigned short bf16bits(float v) {
    __hip_bfloat16 h = __float2bfloat16(v);
    return *(unsigned short*)&h;
}
__device__ __forceinline__ float bf16tof(unsigned short u) {
    __hip_bfloat16 h = *(__hip_bfloat16*)&u;
    return __bfloat162float(h);
}

// ===========================================================================
// one-time per-launch edge sort by index_out (counting sort) — verified r4/r5
// ===========================================================================
__global__ void k_hist(const int* __restrict__ iout, unsigned* __restrict__ cnt) {
    int t = blockIdx.x * 256 + threadIdx.x;
    atomicAdd(&cnt[iout[t]], 1u);
}

__global__ void k_scan(const unsigned* __restrict__ cnt, unsigned* __restrict__ row) {
    __shared__ unsigned part[256];
    int i = threadIdx.x;
    unsigned s = 0;
    if (i < 250) {
        for (int k = 0; k < 80; ++k) s += cnt[i * 80 + k];
    }
    part[i] = s;
    __syncthreads();
    for (int off = 1; off < 256; off <<= 1) {
        unsigned v = part[i];
        unsigned u = (i >= off) ? part[i - off] : 0u;
        __syncthreads();
        part[i] = v + u;
        __syncthreads();
    }
    unsigned run = (i == 0) ? 0u : part[i - 1];
    if (i < 250) {
        for (int k = 0; k < 80; ++k) {
            row[i * 80 + k] = run;
            run += cnt[i * 80 + k];
        }
    }
}

__global__ void k_scatter(const int* __restrict__ iout,
                          const unsigned* __restrict__ row,
                          unsigned* __restrict__ cur,
                          unsigned* __restrict__ perm) {
    int t = blockIdx.x * 256 + threadIdx.x;
    int io = iout[t];
    unsigned pos = row[io] + atomicAdd(&cur[io], 1u);
    perm[pos] = (unsigned)t;
}

__global__ void k_mat(const unsigned* __restrict__ perm,
                      const int* __restrict__ iout, const int* __restrict__ iin,
                      const float* __restrict__ Jm,
                      int* __restrict__ sout, int* __restrict__ sin,
                      float* __restrict__ sJ) {
    int t = blockIdx.x * 256 + threadIdx.x;
    unsigned e = perm[t];
    sout[t] = iout[e];
    sin[t]  = iin[e];
#pragma unroll
    for (int b = 0; b < NBATCH; ++b)
        sJ[(size_t)b * EE + t] = Jm[(size_t)b * EE + e];
}

// ===========================================================================
// prep: W2^T as per-lane MFMA A-fragment images — TRIPLE bf16 split.
// A-frag (qt,kt), lane l, elem j = W2[k = kt*32+8*(l>>4)+j][out = qt*16+(l&15)]
// flat idx t = ((qt*2+kt)*64 + l)*8 + j
// w3img: [qt][l][r][i] = W3[(qt*16 + 4*(l>>4) + r)*5 + i]
// ===========================================================================
__global__ void k_wfrag(const float* __restrict__ W2, const float* __restrict__ W3,
                        unsigned short* __restrict__ af0, unsigned short* __restrict__ af1,
                        unsigned short* __restrict__ af2, float* __restrict__ w3img) {
    int t = blockIdx.x * 256 + threadIdx.x;
    if (t < 4096) {
        int j  = t & 7;
        int l  = (t >> 3) & 63;
        int kt = (t >> 9) & 1;
        int qt = t >> 10;
        int k  = kt * 32 + 8 * (l >> 4) + j;
        int q  = qt * 16 + (l & 15);
        float v = W2[k * 64 + q];
        unsigned short u0 = bf16bits(v);
        float r1 = v - bf16tof(u0);
        unsigned short u1 = bf16bits(r1);
        float r2 = r1 - bf16tof(u1);
        af0[t] = u0;
        af1[t] = u1;
        af2[t] = bf16bits(r2);
    }
    if (t < 5120) {
        int i  = t % 5;
        int r  = (t / 5) & 3;
        int l  = (t / 20) & 63;
        int qt = t / 1280;
        int q  = qt * 16 + 4 * (l >> 4) + r;
        w3img[t] = W3[q * 5 + i];
    }
}

// ===========================================================================
// MFMA message kernel. One wave = 64 sorted edges (one batch).
//   Z2^T[64 out][64 edge] = W2^T (A frags) @ A1^T (B frags, built in regs) + b2
// r6/r7 failure root-caused: layer-2 bias b2 was NEVER added (D init = 0) —
// split-invariant deterministic 1.37e-2 error. Fix: D[et] initialized with
// b2[q] where lane's D rows are q = qt*16 + 4g + r (verified C/D layout).
// Split precision: both operands 3-way bf16 split; 6 MFMA terms per tile.
// Epilogue: relu + W3 dot -> shfl_xor(16,32) reduce -> lane owns its edge ->
// verified segmented scan + tail atomics.
// grid: (EE/256, NBATCH), block 256 (4 waves), no LDS.
// ===========================================================================
__global__ void __launch_bounds__(256, 2) msg_kernel(
    const float* __restrict__ sJ, const float* __restrict__ bnode,
    const int* __restrict__ sin, const int* __restrict__ sout,
    const float* __restrict__ W1, const float* __restrict__ b1,
    const unsigned short* __restrict__ af0, const unsigned short* __restrict__ af1,
    const unsigned short* __restrict__ af2,
    const float* __restrict__ w3img, const float* __restrict__ b2,
    const float* __restrict__ b3,
    const float* __restrict__ h1,
    float* __restrict__ sCur)
{
    int wid  = threadIdx.x >> 6;
    int lane = threadIdx.x & 63;
    int g = lane >> 4;
    int c = lane & 15;
    int E0 = blockIdx.x * 256 + wid * 64;
    int bb = blockIdx.y;
    int e  = E0 + lane;

    int io = sout[e];
    int ii = sin[e];
    size_t hoff = ((size_t)bb * NN + io) * Hd;

    // own-edge features (broadcast sources)
    float xf[8];
#pragma unroll
    for (int i = 0; i < Hd; ++i) xf[i] = h1[hoff + i];
    xf[5] = bnode[bb * NN + ii];
    xf[6] = bnode[bb * NN + io];
    xf[7] = sJ[(size_t)bb * EE + e];

    // ---- layer 1 -> B-operand fragments (triple bf16 split), in registers ----
    short8 B0[4][2], B1f[4][2], B2f[4][2];
#pragma unroll
    for (int kt = 0; kt < 2; ++kt) {
        float w1s[9][8];
#pragma unroll
        for (int f = 0; f < 9; ++f) {
            const float* p = W1 + f * 64 + kt * 32 + 8 * g;
            float4 a0v = *(const float4*)p;
            float4 a1v = *(const float4*)(p + 4);
            w1s[f][0] = a0v.x; w1s[f][1] = a0v.y; w1s[f][2] = a0v.z; w1s[f][3] = a0v.w;
            w1s[f][4] = a1v.x; w1s[f][5] = a1v.y; w1s[f][6] = a1v.z; w1s[f][7] = a1v.w;
        }
        float b1s[8];
        {
            const float* p = b1 + kt * 32 + 8 * g;
            float4 a0v = *(const float4*)p;
            float4 a1v = *(const float4*)(p + 4);
            b1s[0] = a0v.x; b1s[1] = a0v.y; b1s[2] = a0v.z; b1s[3] = a0v.w;
            b1s[4] = a1v.x; b1s[5] = a1v.y; b1s[6] = a1v.z; b1s[7] = a1v.w;
        }
        float w1d[8];   // fold x8 = -jm:  jm * (W1[7] - W1[8])
#pragma unroll
        for (int j = 0; j < 8; ++j) w1d[j] = w1s[7][j] - w1s[8][j];

#pragma unroll
        for (int et = 0; et < 4; ++et) {
            float xe[8];
#pragma unroll
            for (int f = 0; f < 8; ++f) xe[f] = __shfl(xf[f], et * 16 + c, 64);

            short8 v0, v1, v2;
#pragma unroll
            for (int j = 0; j < 8; ++j) {
                float v = b1s[j];
                v = fmaf(xe[0], w1s[0][j], v);
                v = fmaf(xe[1], w1s[1][j], v);
                v = fmaf(xe[2], w1s[2][j], v);
                v = fmaf(xe[3], w1s[3][j], v);
                v = fmaf(xe[4], w1s[4][j], v);
                v = fmaf(xe[5], w1s[5][j], v);
                v = fmaf(xe[6], w1s[6][j], v);
                v = fmaf(xe[7], w1d[j], v);
                v = fmaxf(v, 0.0f);
                unsigned short u0 = bf16bits(v);
                float r1 = v - bf16tof(u0);
                unsigned short u1 = bf16bits(r1);
                float r2 = r1 - bf16tof(u1);
                v0[j] = (short)u0;
                v1[j] = (short)u1;
                v2[j] = (short)bf16bits(r2);
            }
            B0[et][kt] = v0;
            B1f[et][kt] = v1;
            B2f[et][kt] = v2;
        }
    }

    // ---- MFMA + epilogue, per qt (keeps D live-set at 16 VGPRs) ----
    const short8* pA0 = (const short8*)af0;
    const short8* pA1 = (const short8*)af1;
    const short8* pA2 = (const short8*)af2;

    float mp[4][Hd];
#pragma unroll
    for (int et = 0; et < 4; ++et)
#pragma unroll
        for (int i = 0; i < Hd; ++i) mp[et][i] = 0.0f;

#pragma unroll
    for (int qt = 0; qt < 4; ++qt) {
        // bias init: lane's D rows are q = qt*16 + 4g + r  ->  b2[qt*16+4g+r]
        float4 bb2 = *(const float4*)(b2 + qt * 16 + 4 * g);
        f32x4 D[4];
#pragma unroll
        for (int et = 0; et < 4; ++et) D[et] = (f32x4){bb2.x, bb2.y, bb2.z, bb2.w};

#pragma unroll
        for (int kt = 0; kt < 2; ++kt) {
            short8 a0 = pA0[(qt * 2 + kt) * 64 + lane];
            short8 a1 = pA1[(qt * 2 + kt) * 64 + lane];
            short8 a2 = pA2[(qt * 2 + kt) * 64 + lane];
#pragma unroll
            for (int et = 0; et < 4; ++et) {
                D[et] = __builtin_amdgcn_mfma_f32_16x16x32_bf16(a0, B0[et][kt],  D[et], 0, 0, 0);
                D[et] = __builtin_amdgcn_mfma_f32_16x16x32_bf16(a0, B1f[et][kt], D[et], 0, 0, 0);
                D[et] = __builtin_amdgcn_mfma_f32_16x16x32_bf16(a1, B0[et][kt],  D[et], 0, 0, 0);
                D[et] = __builtin_amdgcn_mfma_f32_16x16x32_bf16(a0, B2f[et][kt], D[et], 0, 0, 0);
                D[et] = __builtin_amdgcn_mfma_f32_16x16x32_bf16(a1, B1f[et][kt], D[et], 0, 0, 0);
                D[et] = __builtin_amdgcn_mfma_f32_16x16x32_bf16(a2, B0[et][kt],  D[et], 0, 0, 0);
            }
        }

        // epilogue for this qt: relu + layer-3 partial dot
        const float4* w3p = (const float4*)(w3img + (qt * 64 + lane) * 20);
        float4 wa = w3p[0], wb = w3p[1], wc = w3p[2], wd = w3p[3], we = w3p[4];
        float w3s[4][5] = {
            { wa.x, wa.y, wa.z, wa.w, wb.x },
            { wb.y, wb.z, wb.w, wc.x, wc.y },
            { wc.z, wc.w, wd.x, wd.y, wd.z },
            { wd.w, we.x, we.y, we.z, we.w } };
#pragma unroll
        for (int et = 0; et < 4; ++et) {
#pragma unroll
            for (int r = 0; r < 4; ++r) {
                float a2v = fmaxf(D[et][r], 0.0f);
#pragma unroll
                for (int i = 0; i < Hd; ++i)
                    mp[et][i] = fmaf(a2v, w3s[r][i], mp[et][i]);
            }
        }
    }

    // reduce across the 4 lane-groups (same edge-col c, different out-rows)
#pragma unroll
    for (int et = 0; et < 4; ++et)
#pragma unroll
        for (int i = 0; i < Hd; ++i) {
            float v = mp[et][i];
            v += __shfl_xor(v, 16, 64);
            v += __shfl_xor(v, 32, 64);
            mp[et][i] = v;
        }

    // lane l's own edge = g*16 + c = lane  ->  pick et == g, add bias
    float m[Hd];
#pragma unroll
    for (int i = 0; i < Hd; ++i) {
        float v = (g == 0) ? mp[0][i] : (g == 1) ? mp[1][i] : (g == 2) ? mp[2][i] : mp[3][i];
        m[i] = v + b3[i];
    }

    // ---- wave segmented sum over sorted keys (verified round-5 code) ----
#pragma unroll
    for (int off = 1; off < 64; off <<= 1) {
        int ko = __shfl_up(io, off, 64);
        bool add = (lane >= off) && (ko == io);
#pragma unroll
        for (int i = 0; i < Hd; ++i) {
            float u = __shfl_up(m[i], off, 64);
            if (add) m[i] += u;
        }
    }
    int nk = __shfl_down(io, 1, 64);
    bool tail = (lane == 63) || (nk != io);
    if (tail) {
#pragma unroll
        for (int i = 0; i < Hd; ++i) atomicAdd(&sCur[hoff + i], m[i]);
    }
}

// ---------------------------------------------------------------------------
// per-node GRU update (unchanged, verified).
// ---------------------------------------------------------------------------
__global__ void node_kernel(
    const float* __restrict__ gzW, const float* __restrict__ gzb,
    const float* __restrict__ grW, const float* __restrict__ grb,
    const float* __restrict__ ghW, const float* __restrict__ ghb,
    float* __restrict__ h1, float* __restrict__ m0,
    float* __restrict__ s0buf, const float* __restrict__ s1buf,
    int zeroPrev)
{
    int t = blockIdx.x * 256 + threadIdx.x;
    if (t >= NBATCH * NN) return;
    size_t off = (size_t)t * Hd;

    float h1v[Hd], m0v[Hd], m1v[Hd];
#pragma unroll
    for (int i = 0; i < Hd; ++i) {
        h1v[i] = h1[off + i];
        float m0n = m0[off + i] + s0buf[off + i];
        m0v[i] = m0n;
        m1v[i] = m0n + s1buf[off + i];
        m0[off + i] = m0n;
        if (zeroPrev) s0buf[off + i] = 0.0f;
    }

    float a[15];
#pragma unroll
    for (int i = 0; i < Hd; ++i) { a[i] = h1v[i]; a[5 + i] = m0v[i]; a[10 + i] = m1v[i]; }

    float z[Hd], r[Hd];
#pragma unroll
    for (int i = 0; i < Hd; ++i) {
        float tz = gzb[i], tr = grb[i];
#pragma unroll
        for (int j = 0; j < 15; ++j) {
            tz = fmaf(a[j], gzW[j * Hd + i], tz);
            tr = fmaf(a[j], grW[j * Hd + i], tr);
        }
        z[i] = sigmoidf_(tz);
        r[i] = sigmoidf_(tr);
    }

    float joined[15];
#pragma unroll
    for (int i = 0; i < Hd; ++i) { joined[i] = r[i] * h1v[i]; joined[5 + i] = m0v[i]; joined[10 + i] = m1v[i]; }

#pragma unroll
    for (int i = 0; i < Hd; ++i) {
        float th = ghb[i];
#pragma unroll
        for (int j = 0; j < 15; ++j) th = fmaf(joined[j], ghW[j * Hd + i], th);
        float hh = tanhf(th);
        h1[off + i] = (1.0f - z[i]) * h1v[i] + z[i] * hh;
    }
}

// ---------------------------------------------------------------------------
// output MLP (unchanged, verified; runs once)
// ---------------------------------------------------------------------------
__global__ void __launch_bounds__(256, 1) out_kernel(
    const float* __restrict__ bnode, const float* __restrict__ h1,
    const float* __restrict__ oW1, const float* __restrict__ ob1,
    const float* __restrict__ oW2, const float* __restrict__ ob2,
    const float* __restrict__ oW3, const float* __restrict__ ob3,
    float* __restrict__ out)
{
    int t = blockIdx.x * 256 + threadIdx.x;
    if (t >= NBATCH * NN) return;

    float x[6];
#pragma unroll
    for (int i = 0; i < Hd; ++i) x[i] = h1[(size_t)t * Hd + i];
    x[5] = bnode[t];

    float acc[64];
#pragma unroll
    for (int q = 0; q < 64; ++q) acc[q] = ob2[q];

#pragma unroll 2
    for (int j = 0; j < 64; ++j) {
        float v = ob1[j];
#pragma unroll
        for (int f = 0; f < 6; ++f) v = fmaf(x[f], oW1[f * 64 + j], v);
        v = fmaxf(v, 0.0f);
        const float* __restrict__ w2r = oW2 + j * 64;
#pragma unroll
        for (int q = 0; q < 64; ++q) acc[q] = fmaf(v, w2r[q], acc[q]);
    }

    float o = ob3[0];
#pragma unroll
    for (int q = 0; q < 64; ++q) o = fmaf(fmaxf(acc[q], 0.0f), oW3[q], o);
    out[t] = sigmoidf_(o);
}

// ---------------------------------------------------------------------------
extern "C" void kernel_launch(void* const* d_in, const int* in_sizes, int n_in,
                              void* d_out, int out_size, void* d_ws, size_t ws_size,
                              hipStream_t stream) {
    const float* Jm    = (const float*)d_in[0];
    const float* bnode = (const float*)d_in[1];
    const int*   iin   = (const int*)d_in[2];
    const int*   iout  = (const int*)d_in[3];
    const float* mW1 = (const float*)d_in[4];
    const float* mb1 = (const float*)d_in[5];
    const float* mW2 = (const float*)d_in[6];
    const float* mb2 = (const float*)d_in[7];
    const float* mW3 = (const float*)d_in[8];
    const float* mb3 = (const float*)d_in[9];
    const float* gzW = (const float*)d_in[10];
    const float* gzb = (const float*)d_in[11];
    const float* grW = (const float*)d_in[12];
    const float* grb = (const float*)d_in[13];
    const float* ghW = (const float*)d_in[14];
    const float* ghb = (const float*)d_in[15];
    const float* oW1 = (const float*)d_in[16];
    const float* ob1 = (const float*)d_in[17];
    const float* oW2 = (const float*)d_in[18];
    const float* ob2 = (const float*)d_in[19];
    const float* oW3 = (const float*)d_in[20];
    const float* ob3 = (const float*)d_in[21];

    float* ws = (float*)d_ws;
    float* h1 = ws;
    float* m0 = ws + (size_t)BNH;
    float* sA = ws + (size_t)2 * BNH;
    float* sB = ws + (size_t)3 * BNH;
    unsigned* cnt  = (unsigned*)(ws + (size_t)4 * BNH);
    unsigned* cur  = cnt + NN;
    unsigned* row  = cur + NN;
    unsigned* perm = row + NN;
    int*      sout = (int*)(perm + EE);
    int*      sin  = sout + EE;
    float*    sJ   = (float*)(sin + EE);           // NBATCH*EE floats
    unsigned short* af0 = (unsigned short*)(sJ + (size_t)NBATCH * EE);  // 3 x 4096 bf16
    unsigned short* af1 = af0 + 4096;
    unsigned short* af2 = af1 + 4096;
    float*    w3img = (float*)(af2 + 4096);                             // 5120 floats

    // zero h1, m0, sA, sB, cnt, cur (contiguous)
    hipMemsetAsync(d_ws, 0, ((size_t)4 * BNH + 2 * NN) * sizeof(float), stream);

    // one-time (per launch): sort edges by index_out + build weight frag images
    k_hist<<<EE / 256, 256, 0, stream>>>(iout, cnt);
    k_scan<<<1, 256, 0, stream>>>(cnt, row);
    k_scatter<<<EE / 256, 256, 0, stream>>>(iout, row, cur, perm);
    k_mat<<<EE / 256, 256, 0, stream>>>(perm, iout, iin, Jm, sout, sin, sJ);
    k_wfrag<<<20, 256, 0, stream>>>(mW2, mW3, af0, af1, af2, w3img);

    dim3 mgrid(EE / 256, NBATCH);
    int ngrid = (NBATCH * NN + 255) / 256;

    float* buf[2] = { sA, sB };
    for (int s = 0; s < 10; ++s) {
        float* sCur  = buf[s & 1];
        float* sPrev = (s == 0) ? sCur : buf[(s + 1) & 1];
        msg_kernel<<<mgrid, 256, 0, stream>>>(sJ, bnode, sin, sout,
                                              mW1, mb1, af0, af1, af2, w3img,
                                              mb2, mb3, h1, sCur);
        node_kernel<<<ngrid, 256, 0, stream>>>(gzW, gzb, grW, grb, ghW, ghb,
                                               h1, m0, sPrev, sCur,
                                               (s == 0) ? 0 : 1);
    }

    out_kernel<<<ngrid, 256, 0, stream>>>(bnode, h1,
                                          oW1, ob1, oW2, ob2, oW3, ob3,
                                          (float*)d_out);
}

// Round 9
// 1045.747 us; speedup vs baseline: 7.3437x; 1.1450x over previous
//
#include <hip/hip_runtime.h>
#include <hip/hip_bf16.h>
#include <math.h>

#define Hd 5
#define NN 20000
#define EE 320000
#define NBATCH 4
#define BNH (NBATCH * NN * Hd) /* 400000 */

typedef __attribute__((ext_vector_type(8))) short short8;
typedef __attribute__((ext_vector_type(4))) float f32x4;
typedef __attribute__((ext_vector_type(4))) unsigned int uint4v;

__device__ __forceinline__ float sigmoidf_(float v) {
    return 1.0f / (1.0f + expf(-v));
}

__device__ __forceinline__ unsigned short bf16bits(float v) {
    __hip_bfloat16 h = __float2bfloat16(v);
    return *(unsigned short*)&h;
}
__device__ __forceinline__ float bf16tof(unsigned short u) {
    __hip_bfloat16 h = *(__hip_bfloat16*)&u;
    return __bfloat162float(h);
}

// ===========================================================================
// one-time per-launch edge sort by index_out (counting sort) — verified r4/r5
// ===========================================================================
__global__ void k_hist(const int* __restrict__ iout, unsigned* __restrict__ cnt) {
    int t = blockIdx.x * 256 + threadIdx.x;
    atomicAdd(&cnt[iout[t]], 1u);
}

__global__ void k_scan(const unsigned* __restrict__ cnt, unsigned* __restrict__ row) {
    __shared__ unsigned part[256];
    int i = threadIdx.x;
    unsigned s = 0;
    if (i < 250) {
        for (int k = 0; k < 80; ++k) s += cnt[i * 80 + k];
    }
    part[i] = s;
    __syncthreads();
    for (int off = 1; off < 256; off <<= 1) {
        unsigned v = part[i];
        unsigned u = (i >= off) ? part[i - off] : 0u;
        __syncthreads();
        part[i] = v + u;
        __syncthreads();
    }
    unsigned run = (i == 0) ? 0u : part[i - 1];
    if (i < 250) {
        for (int k = 0; k < 80; ++k) {
            row[i * 80 + k] = run;
            run += cnt[i * 80 + k];
        }
    }
}

__global__ void k_scatter(const int* __restrict__ iout,
                          const unsigned* __restrict__ row,
                          unsigned* __restrict__ cur,
                          unsigned* __restrict__ perm) {
    int t = blockIdx.x * 256 + threadIdx.x;
    int io = iout[t];
    unsigned pos = row[io] + atomicAdd(&cur[io], 1u);
    perm[pos] = (unsigned)t;
}

__global__ void k_mat(const unsigned* __restrict__ perm,
                      const int* __restrict__ iout, const int* __restrict__ iin,
                      const float* __restrict__ Jm,
                      int* __restrict__ sout, int* __restrict__ sin,
                      float* __restrict__ sJ) {
    int t = blockIdx.x * 256 + threadIdx.x;
    unsigned e = perm[t];
    sout[t] = iout[e];
    sin[t]  = iin[e];
#pragma unroll
    for (int b = 0; b < NBATCH; ++b)
        sJ[(size_t)b * EE + t] = Jm[(size_t)b * EE + e];
}

// ===========================================================================
// prep: W2^T as per-lane MFMA A-fragment images (2-way RNE bf16 split).
// A-frag (qt,kt), lane l, elem j = W2[k = kt*32+8*(l>>4)+j][out = qt*16+(l&15)]
// flat idx t = ((qt*2+kt)*64 + l)*8 + j
// w3img: [qt][l][r][i] = W3[(qt*16 + 4*(l>>4) + r)*5 + i]
// ===========================================================================
__global__ void k_wfrag(const float* __restrict__ W2, const float* __restrict__ W3,
                        unsigned short* __restrict__ af0, unsigned short* __restrict__ af1,
                        float* __restrict__ w3img) {
    int t = blockIdx.x * 256 + threadIdx.x;
    if (t < 4096) {
        int j  = t & 7;
        int l  = (t >> 3) & 63;
        int kt = (t >> 9) & 1;
        int qt = t >> 10;
        int k  = kt * 32 + 8 * (l >> 4) + j;
        int q  = qt * 16 + (l & 15);
        float v = W2[k * 64 + q];
        unsigned short u0 = bf16bits(v);
        float r1 = v - bf16tof(u0);
        af0[t] = u0;
        af1[t] = bf16bits(r1);
    }
    if (t < 5120) {
        int i  = t % 5;
        int r  = (t / 5) & 3;
        int l  = (t / 20) & 63;
        int qt = t / 1280;
        int q  = qt * 16 + 4 * (l >> 4) + r;
        w3img[t] = W3[q * 5 + i];
    }
}

// ===========================================================================
// MFMA message kernel. One wave = 64 sorted edges (one batch).
//   Z2^T[64 out][64 edge] = W2^T (A frags) @ A1^T (B frags, built in regs) + b2
// b2 applied via D-accumulator init (r8 fix, verified: absmax 0.0).
// Split precision (r9): 2-way split both sides, 3 MFMA terms
//   a0b0 + a0b1 + a1b0   (error ~2^-16 rel; r6 vs r7 bit-identical absmax
//   shows 3-vs-6-term difference is below bf16-output visibility).
// B-side split/pack is TRUNCATION-based, pure bit-ops (no cvt chains):
//   b0 = bits&0xFFFF0000 (exact sub for residual), dword pack = and_or + lshr.
// Epilogue: relu + W3 dot -> shfl_xor(16,32) reduce -> lane owns its edge ->
// verified segmented scan + tail atomics.
// grid: (EE/256, NBATCH), block 256 (4 waves), no LDS.
// ===========================================================================
__global__ void __launch_bounds__(256, 2) msg_kernel(
    const float* __restrict__ sJ, const float* __restrict__ bnode,
    const int* __restrict__ sin, const int* __restrict__ sout,
    const float* __restrict__ W1, const float* __restrict__ b1,
    const unsigned short* __restrict__ af0, const unsigned short* __restrict__ af1,
    const float* __restrict__ w3img, const float* __restrict__ b2,
    const float* __restrict__ b3,
    const float* __restrict__ h1,
    float* __restrict__ sCur)
{
    int wid  = threadIdx.x >> 6;
    int lane = threadIdx.x & 63;
    int g = lane >> 4;
    int c = lane & 15;
    int E0 = blockIdx.x * 256 + wid * 64;
    int bb = blockIdx.y;
    int e  = E0 + lane;

    int io = sout[e];
    int ii = sin[e];
    size_t hoff = ((size_t)bb * NN + io) * Hd;

    // own-edge features (broadcast sources)
    float xf[8];
#pragma unroll
    for (int i = 0; i < Hd; ++i) xf[i] = h1[hoff + i];
    xf[5] = bnode[bb * NN + ii];
    xf[6] = bnode[bb * NN + io];
    xf[7] = sJ[(size_t)bb * EE + e];

    // ---- layer 1 -> B-operand fragments (2-way truncation split), in regs ----
    short8 B0[4][2], B1f[4][2];
#pragma unroll
    for (int kt = 0; kt < 2; ++kt) {
        float w1s[9][8];
#pragma unroll
        for (int f = 0; f < 9; ++f) {
            const float* p = W1 + f * 64 + kt * 32 + 8 * g;
            float4 a0v = *(const float4*)p;
            float4 a1v = *(const float4*)(p + 4);
            w1s[f][0] = a0v.x; w1s[f][1] = a0v.y; w1s[f][2] = a0v.z; w1s[f][3] = a0v.w;
            w1s[f][4] = a1v.x; w1s[f][5] = a1v.y; w1s[f][6] = a1v.z; w1s[f][7] = a1v.w;
        }
        float b1s[8];
        {
            const float* p = b1 + kt * 32 + 8 * g;
            float4 a0v = *(const float4*)p;
            float4 a1v = *(const float4*)(p + 4);
            b1s[0] = a0v.x; b1s[1] = a0v.y; b1s[2] = a0v.z; b1s[3] = a0v.w;
            b1s[4] = a1v.x; b1s[5] = a1v.y; b1s[6] = a1v.z; b1s[7] = a1v.w;
        }
        float w1d[8];   // fold x8 = -jm:  jm * (W1[7] - W1[8])
#pragma unroll
        for (int j = 0; j < 8; ++j) w1d[j] = w1s[7][j] - w1s[8][j];

#pragma unroll
        for (int et = 0; et < 4; ++et) {
            float xe[8];
#pragma unroll
            for (int f = 0; f < 8; ++f) xe[f] = __shfl(xf[f], et * 16 + c, 64);

            uint4v w0, w1p;
#pragma unroll
            for (int j2 = 0; j2 < 4; ++j2) {
                float va, vb;
#pragma unroll
                for (int half = 0; half < 2; ++half) {
                    int j = 2 * j2 + half;
                    float v = b1s[j];
                    v = fmaf(xe[0], w1s[0][j], v);
                    v = fmaf(xe[1], w1s[1][j], v);
                    v = fmaf(xe[2], w1s[2][j], v);
                    v = fmaf(xe[3], w1s[3][j], v);
                    v = fmaf(xe[4], w1s[4][j], v);
                    v = fmaf(xe[5], w1s[5][j], v);
                    v = fmaf(xe[6], w1s[6][j], v);
                    v = fmaf(xe[7], w1d[j], v);
                    v = fmaxf(v, 0.0f);
                    if (half == 0) va = v; else vb = v;
                }
                unsigned ta = __float_as_uint(va), tb = __float_as_uint(vb);
                unsigned ha = ta & 0xFFFF0000u, hb = tb & 0xFFFF0000u;
                w0[j2] = hb | (ta >> 16);                  // level-0 bf16 pair
                float ra = va - __uint_as_float(ha);       // exact residual
                float rb = vb - __uint_as_float(hb);
                unsigned sa = __float_as_uint(ra), sb = __float_as_uint(rb);
                w1p[j2] = (sb & 0xFFFF0000u) | (sa >> 16); // level-1 bf16 pair
            }
            B0[et][kt]  = __builtin_bit_cast(short8, w0);
            B1f[et][kt] = __builtin_bit_cast(short8, w1p);
        }
    }

    // ---- MFMA + epilogue, per qt (keeps D live-set at 16 VGPRs) ----
    const short8* pA0 = (const short8*)af0;
    const short8* pA1 = (const short8*)af1;

    float mp[4][Hd];
#pragma unroll
    for (int et = 0; et < 4; ++et)
#pragma unroll
        for (int i = 0; i < Hd; ++i) mp[et][i] = 0.0f;

#pragma unroll
    for (int qt = 0; qt < 4; ++qt) {
        // bias init: lane's D rows are q = qt*16 + 4g + r  ->  b2[qt*16+4g+r]
        float4 bb2 = *(const float4*)(b2 + qt * 16 + 4 * g);
        f32x4 D[4];
#pragma unroll
        for (int et = 0; et < 4; ++et) D[et] = (f32x4){bb2.x, bb2.y, bb2.z, bb2.w};

#pragma unroll
        for (int kt = 0; kt < 2; ++kt) {
            short8 a0 = pA0[(qt * 2 + kt) * 64 + lane];
            short8 a1 = pA1[(qt * 2 + kt) * 64 + lane];
#pragma unroll
            for (int et = 0; et < 4; ++et) {
                D[et] = __builtin_amdgcn_mfma_f32_16x16x32_bf16(a0, B0[et][kt],  D[et], 0, 0, 0);
                D[et] = __builtin_amdgcn_mfma_f32_16x16x32_bf16(a0, B1f[et][kt], D[et], 0, 0, 0);
                D[et] = __builtin_amdgcn_mfma_f32_16x16x32_bf16(a1, B0[et][kt],  D[et], 0, 0, 0);
            }
        }

        // epilogue for this qt: relu + layer-3 partial dot
        const float4* w3p = (const float4*)(w3img + (qt * 64 + lane) * 20);
        float4 wa = w3p[0], wb = w3p[1], wc = w3p[2], wd = w3p[3], we = w3p[4];
        float w3s[4][5] = {
            { wa.x, wa.y, wa.z, wa.w, wb.x },
            { wb.y, wb.z, wb.w, wc.x, wc.y },
            { wc.z, wc.w, wd.x, wd.y, wd.z },
            { wd.w, we.x, we.y, we.z, we.w } };
#pragma unroll
        for (int et = 0; et < 4; ++et) {
#pragma unroll
            for (int r = 0; r < 4; ++r) {
                float a2v = fmaxf(D[et][r], 0.0f);
#pragma unroll
                for (int i = 0; i < Hd; ++i)
                    mp[et][i] = fmaf(a2v, w3s[r][i], mp[et][i]);
            }
        }
    }

    // reduce across the 4 lane-groups (same edge-col c, different out-rows)
#pragma unroll
    for (int et = 0; et < 4; ++et)
#pragma unroll
        for (int i = 0; i < Hd; ++i) {
            float v = mp[et][i];
            v += __shfl_xor(v, 16, 64);
            v += __shfl_xor(v, 32, 64);
            mp[et][i] = v;
        }

    // lane l's own edge = g*16 + c = lane  ->  pick et == g, add bias
    float m[Hd];
#pragma unroll
    for (int i = 0; i < Hd; ++i) {
        float v = (g == 0) ? mp[0][i] : (g == 1) ? mp[1][i] : (g == 2) ? mp[2][i] : mp[3][i];
        m[i] = v + b3[i];
    }

    // ---- wave segmented sum over sorted keys (verified round-5 code) ----
#pragma unroll
    for (int off = 1; off < 64; off <<= 1) {
        int ko = __shfl_up(io, off, 64);
        bool add = (lane >= off) && (ko == io);
#pragma unroll
        for (int i = 0; i < Hd; ++i) {
            float u = __shfl_up(m[i], off, 64);
            if (add) m[i] += u;
        }
    }
    int nk = __shfl_down(io, 1, 64);
    bool tail = (lane == 63) || (nk != io);
    if (tail) {
#pragma unroll
        for (int i = 0; i < Hd; ++i) atomicAdd(&sCur[hoff + i], m[i]);
    }
}

// ---------------------------------------------------------------------------
// per-node GRU update (unchanged, verified).
// ---------------------------------------------------------------------------
__global__ void node_kernel(
    const float* __restrict__ gzW, const float* __restrict__ gzb,
    const float* __restrict__ grW, const float* __restrict__ grb,
    const float* __restrict__ ghW, const float* __restrict__ ghb,
    float* __restrict__ h1, float* __restrict__ m0,
    float* __restrict__ s0buf, const float* __restrict__ s1buf,
    int zeroPrev)
{
    int t = blockIdx.x * 256 + threadIdx.x;
    if (t >= NBATCH * NN) return;
    size_t off = (size_t)t * Hd;

    float h1v[Hd], m0v[Hd], m1v[Hd];
#pragma unroll
    for (int i = 0; i < Hd; ++i) {
        h1v[i] = h1[off + i];
        float m0n = m0[off + i] + s0buf[off + i];
        m0v[i] = m0n;
        m1v[i] = m0n + s1buf[off + i];
        m0[off + i] = m0n;
        if (zeroPrev) s0buf[off + i] = 0.0f;
    }

    float a[15];
#pragma unroll
    for (int i = 0; i < Hd; ++i) { a[i] = h1v[i]; a[5 + i] = m0v[i]; a[10 + i] = m1v[i]; }

    float z[Hd], r[Hd];
#pragma unroll
    for (int i = 0; i < Hd; ++i) {
        float tz = gzb[i], tr = grb[i];
#pragma unroll
        for (int j = 0; j < 15; ++j) {
            tz = fmaf(a[j], gzW[j * Hd + i], tz);
            tr = fmaf(a[j], grW[j * Hd + i], tr);
        }
        z[i] = sigmoidf_(tz);
        r[i] = sigmoidf_(tr);
    }

    float joined[15];
#pragma unroll
    for (int i = 0; i < Hd; ++i) { joined[i] = r[i] * h1v[i]; joined[5 + i] = m0v[i]; joined[10 + i] = m1v[i]; }

#pragma unroll
    for (int i = 0; i < Hd; ++i) {
        float th = ghb[i];
#pragma unroll
        for (int j = 0; j < 15; ++j) th = fmaf(joined[j], ghW[j * Hd + i], th);
        float hh = tanhf(th);
        h1[off + i] = (1.0f - z[i]) * h1v[i] + z[i] * hh;
    }
}

// ---------------------------------------------------------------------------
// output MLP (unchanged, verified; runs once)
// ---------------------------------------------------------------------------
__global__ void __launch_bounds__(256, 1) out_kernel(
    const float* __restrict__ bnode, const float* __restrict__ h1,
    const float* __restrict__ oW1, const float* __restrict__ ob1,
    const float* __restrict__ oW2, const float* __restrict__ ob2,
    const float* __restrict__ oW3, const float* __restrict__ ob3,
    float* __restrict__ out)
{
    int t = blockIdx.x * 256 + threadIdx.x;
    if (t >= NBATCH * NN) return;

    float x[6];
#pragma unroll
    for (int i = 0; i < Hd; ++i) x[i] = h1[(size_t)t * Hd + i];
    x[5] = bnode[t];

    float acc[64];
#pragma unroll
    for (int q = 0; q < 64; ++q) acc[q] = ob2[q];

#pragma unroll 2
    for (int j = 0; j < 64; ++j) {
        float v = ob1[j];
#pragma unroll
        for (int f = 0; f < 6; ++f) v = fmaf(x[f], oW1[f * 64 + j], v);
        v = fmaxf(v, 0.0f);
        const float* __restrict__ w2r = oW2 + j * 64;
#pragma unroll
        for (int q = 0; q < 64; ++q) acc[q] = fmaf(v, w2r[q], acc[q]);
    }

    float o = ob3[0];
#pragma unroll
    for (int q = 0; q < 64; ++q) o = fmaf(fmaxf(acc[q], 0.0f), oW3[q], o);
    out[t] = sigmoidf_(o);
}

// ---------------------------------------------------------------------------
extern "C" void kernel_launch(void* const* d_in, const int* in_sizes, int n_in,
                              void* d_out, int out_size, void* d_ws, size_t ws_size,
                              hipStream_t stream) {
    const float* Jm    = (const float*)d_in[0];
    const float* bnode = (const float*)d_in[1];
    const int*   iin   = (const int*)d_in[2];
    const int*   iout  = (const int*)d_in[3];
    const float* mW1 = (const float*)d_in[4];
    const float* mb1 = (const float*)d_in[5];
    const float* mW2 = (const float*)d_in[6];
    const float* mb2 = (const float*)d_in[7];
    const float* mW3 = (const float*)d_in[8];
    const float* mb3 = (const float*)d_in[9];
    const float* gzW = (const float*)d_in[10];
    const float* gzb = (const float*)d_in[11];
    const float* grW = (const float*)d_in[12];
    const float* grb = (const float*)d_in[13];
    const float* ghW = (const float*)d_in[14];
    const float* ghb = (const float*)d_in[15];
    const float* oW1 = (const float*)d_in[16];
    const float* ob1 = (const float*)d_in[17];
    const float* oW2 = (const float*)d_in[18];
    const float* ob2 = (const float*)d_in[19];
    const float* oW3 = (const float*)d_in[20];
    const float* ob3 = (const float*)d_in[21];

    float* ws = (float*)d_ws;
    float* h1 = ws;
    float* m0 = ws + (size_t)BNH;
    float* sA = ws + (size_t)2 * BNH;
    float* sB = ws + (size_t)3 * BNH;
    unsigned* cnt  = (unsigned*)(ws + (size_t)4 * BNH);
    unsigned* cur  = cnt + NN;
    unsigned* row  = cur + NN;
    unsigned* perm = row + NN;
    int*      sout = (int*)(perm + EE);
    int*      sin  = sout + EE;
    float*    sJ   = (float*)(sin + EE);           // NBATCH*EE floats
    unsigned short* af0 = (unsigned short*)(sJ + (size_t)NBATCH * EE);  // 2 x 4096 bf16
    unsigned short* af1 = af0 + 4096;
    float*    w3img = (float*)(af1 + 4096);                             // 5120 floats

    // zero h1, m0, sA, sB, cnt, cur (contiguous)
    hipMemsetAsync(d_ws, 0, ((size_t)4 * BNH + 2 * NN) * sizeof(float), stream);

    // one-time (per launch): sort edges by index_out + build weight frag images
    k_hist<<<EE / 256, 256, 0, stream>>>(iout, cnt);
    k_scan<<<1, 256, 0, stream>>>(cnt, row);
    k_scatter<<<EE / 256, 256, 0, stream>>>(iout, row, cur, perm);
    k_mat<<<EE / 256, 256, 0, stream>>>(perm, iout, iin, Jm, sout, sin, sJ);
    k_wfrag<<<20, 256, 0, stream>>>(mW2, mW3, af0, af1, w3img);

    dim3 mgrid(EE / 256, NBATCH);
    int ngrid = (NBATCH * NN + 255) / 256;

    float* buf[2] = { sA, sB };
    for (int s = 0; s < 10; ++s) {
        float* sCur  = buf[s & 1];
        float* sPrev = (s == 0) ? sCur : buf[(s + 1) & 1];
        msg_kernel<<<mgrid, 256, 0, stream>>>(sJ, bnode, sin, sout,
                                              mW1, mb1, af0, af1, w3img,
                                              mb2, mb3, h1, sCur);
        node_kernel<<<ngrid, 256, 0, stream>>>(gzW, gzb, grW, grb, ghW, ghb,
                                               h1, m0, sPrev, sCur,
                                               (s == 0) ? 0 : 1);
    }

    out_kernel<<<ngrid, 256, 0, stream>>>(bnode, h1,
                                          oW1, ob1, oW2, ob2, oW3, ob3,
                                          (float*)d_out);
}

// Round 10
// 927.656 us; speedup vs baseline: 8.2786x; 1.1273x over previous
//
#include <hip/hip_runtime.h>
#include <hip/hip_bf16.h>
#include <math.h>

#define Hd 5
#define NN 20000
#define EE 320000
#define NBATCH 4
#define BNH (NBATCH * NN * Hd) /* 400000 */

typedef __attribute__((ext_vector_type(8))) short short8;
typedef __attribute__((ext_vector_type(4))) float f32x4;
typedef __attribute__((ext_vector_type(4))) unsigned int uint4v;

__device__ __forceinline__ float sigmoidf_(float v) {
    return 1.0f / (1.0f + expf(-v));
}

__device__ __forceinline__ unsigned short bf16bits(float v) {
    __hip_bfloat16 h = __float2bfloat16(v);
    return *(unsigned short*)&h;
}

// ===========================================================================
// one-time per-launch edge sort by index_out (counting sort) — verified r4/r5
// ===========================================================================
__global__ void k_hist(const int* __restrict__ iout, unsigned* __restrict__ cnt) {
    int t = blockIdx.x * 256 + threadIdx.x;
    atomicAdd(&cnt[iout[t]], 1u);
}

__global__ void k_scan(const unsigned* __restrict__ cnt, unsigned* __restrict__ row) {
    __shared__ unsigned part[256];
    int i = threadIdx.x;
    unsigned s = 0;
    if (i < 250) {
        for (int k = 0; k < 80; ++k) s += cnt[i * 80 + k];
    }
    part[i] = s;
    __syncthreads();
    for (int off = 1; off < 256; off <<= 1) {
        unsigned v = part[i];
        unsigned u = (i >= off) ? part[i - off] : 0u;
        __syncthreads();
        part[i] = v + u;
        __syncthreads();
    }
    unsigned run = (i == 0) ? 0u : part[i - 1];
    if (i < 250) {
        for (int k = 0; k < 80; ++k) {
            row[i * 80 + k] = run;
            run += cnt[i * 80 + k];
        }
    }
}

__global__ void k_scatter(const int* __restrict__ iout,
                          const unsigned* __restrict__ row,
                          unsigned* __restrict__ cur,
                          unsigned* __restrict__ perm) {
    int t = blockIdx.x * 256 + threadIdx.x;
    int io = iout[t];
    unsigned pos = row[io] + atomicAdd(&cur[io], 1u);
    perm[pos] = (unsigned)t;
}

__global__ void k_mat(const unsigned* __restrict__ perm,
                      const int* __restrict__ iout, const int* __restrict__ iin,
                      const float* __restrict__ Jm,
                      int* __restrict__ sout, int* __restrict__ sin,
                      float* __restrict__ sJ) {
    int t = blockIdx.x * 256 + threadIdx.x;
    unsigned e = perm[t];
    sout[t] = iout[e];
    sin[t]  = iin[e];
#pragma unroll
    for (int b = 0; b < NBATCH; ++b)
        sJ[(size_t)b * EE + t] = Jm[(size_t)b * EE + e];
}

// ===========================================================================
// prep: W2^T as per-lane MFMA A-fragment images (single RNE bf16 image).
// A-frag (qt,kt), lane l, elem j = W2[k = kt*32+8*(l>>4)+j][out = qt*16+(l&15)]
// flat idx t = ((qt*2+kt)*64 + l)*8 + j
// w3img: [qt][l][r][i] = W3[(qt*16 + 4*(l>>4) + r)*5 + i]
// ===========================================================================
__global__ void k_wfrag(const float* __restrict__ W2, const float* __restrict__ W3,
                        unsigned short* __restrict__ af0, float* __restrict__ w3img) {
    int t = blockIdx.x * 256 + threadIdx.x;
    if (t < 4096) {
        int j  = t & 7;
        int l  = (t >> 3) & 63;
        int kt = (t >> 9) & 1;
        int qt = t >> 10;
        int k  = kt * 32 + 8 * (l >> 4) + j;
        int q  = qt * 16 + (l & 15);
        af0[t] = bf16bits(W2[k * 64 + q]);
    }
    if (t < 5120) {
        int i  = t % 5;
        int r  = (t / 5) & 3;
        int l  = (t / 20) & 63;
        int qt = t / 1280;
        int q  = qt * 16 + 4 * (l >> 4) + r;
        w3img[t] = W3[q * 5 + i];
    }
}

// ===========================================================================
// MFMA message kernel. One wave = 64 sorted edges (one batch).
//   Z2^T[64 out][64 edge] = W2^T (A frags) @ A1^T (B frags, built in regs) + b2
// b2 applied via D-accumulator init (r8 fix, verified: absmax 0.0).
// Precision (r10 experiment): PLAIN RNE bf16, single MFMA term. Rationale:
// r9 (3-term) absmax = 0.0 in bf16-output domain (big headroom vs 9.96e-3);
// r6 calibration: systematic |b2|~0.06 Z2 error -> 1.37e-2 final; incoherent
// bf16 rounding (~4e-3 rel on Z2) should land ~1-3e-3 final.
// FAILURE SIGNATURE (pre-registered): absmax ~1.5-3e-2 => revert to 2-term.
// B-pack: one v_cvt_pk_bf16_f32 per f32 pair (RNE, no trunc bias).
// Epilogue: relu + W3 dot -> shfl_xor(16,32) reduce -> lane owns its edge ->
// verified segmented scan + tail atomics.
// grid: (EE/256, NBATCH), block 256 (4 waves), no LDS.
// ===========================================================================
__global__ void __launch_bounds__(256, 2) msg_kernel(
    const float* __restrict__ sJ, const float* __restrict__ bnode,
    const int* __restrict__ sin, const int* __restrict__ sout,
    const float* __restrict__ W1, const float* __restrict__ b1,
    const unsigned short* __restrict__ af0,
    const float* __restrict__ w3img, const float* __restrict__ b2,
    const float* __restrict__ b3,
    const float* __restrict__ h1,
    float* __restrict__ sCur)
{
    int wid  = threadIdx.x >> 6;
    int lane = threadIdx.x & 63;
    int g = lane >> 4;
    int c = lane & 15;
    int E0 = blockIdx.x * 256 + wid * 64;
    int bb = blockIdx.y;
    int e  = E0 + lane;

    int io = sout[e];
    int ii = sin[e];
    size_t hoff = ((size_t)bb * NN + io) * Hd;

    // own-edge features (broadcast sources)
    float xf[8];
#pragma unroll
    for (int i = 0; i < Hd; ++i) xf[i] = h1[hoff + i];
    xf[5] = bnode[bb * NN + ii];
    xf[6] = bnode[bb * NN + io];
    xf[7] = sJ[(size_t)bb * EE + e];

    // ---- layer 1 -> B-operand fragments (plain RNE bf16), in registers ----
    short8 B0[4][2];
#pragma unroll
    for (int kt = 0; kt < 2; ++kt) {
        float w1s[9][8];
#pragma unroll
        for (int f = 0; f < 9; ++f) {
            const float* p = W1 + f * 64 + kt * 32 + 8 * g;
            float4 a0v = *(const float4*)p;
            float4 a1v = *(const float4*)(p + 4);
            w1s[f][0] = a0v.x; w1s[f][1] = a0v.y; w1s[f][2] = a0v.z; w1s[f][3] = a0v.w;
            w1s[f][4] = a1v.x; w1s[f][5] = a1v.y; w1s[f][6] = a1v.z; w1s[f][7] = a1v.w;
        }
        float b1s[8];
        {
            const float* p = b1 + kt * 32 + 8 * g;
            float4 a0v = *(const float4*)p;
            float4 a1v = *(const float4*)(p + 4);
            b1s[0] = a0v.x; b1s[1] = a0v.y; b1s[2] = a0v.z; b1s[3] = a0v.w;
            b1s[4] = a1v.x; b1s[5] = a1v.y; b1s[6] = a1v.z; b1s[7] = a1v.w;
        }
        float w1d[8];   // fold x8 = -jm:  jm * (W1[7] - W1[8])
#pragma unroll
        for (int j = 0; j < 8; ++j) w1d[j] = w1s[7][j] - w1s[8][j];

#pragma unroll
        for (int et = 0; et < 4; ++et) {
            float xe[8];
#pragma unroll
            for (int f = 0; f < 8; ++f) xe[f] = __shfl(xf[f], et * 16 + c, 64);

            uint4v w0;
#pragma unroll
            for (int j2 = 0; j2 < 4; ++j2) {
                float va, vb;
#pragma unroll
                for (int half = 0; half < 2; ++half) {
                    int j = 2 * j2 + half;
                    float v = b1s[j];
                    v = fmaf(xe[0], w1s[0][j], v);
                    v = fmaf(xe[1], w1s[1][j], v);
                    v = fmaf(xe[2], w1s[2][j], v);
                    v = fmaf(xe[3], w1s[3][j], v);
                    v = fmaf(xe[4], w1s[4][j], v);
                    v = fmaf(xe[5], w1s[5][j], v);
                    v = fmaf(xe[6], w1s[6][j], v);
                    v = fmaf(xe[7], w1d[j], v);
                    v = fmaxf(v, 0.0f);
                    if (half == 0) va = v; else vb = v;
                }
                unsigned pk;
                asm("v_cvt_pk_bf16_f32 %0, %1, %2" : "=v"(pk) : "v"(va), "v"(vb));
                w0[j2] = pk;   // lo16 = bf16(va), hi16 = bf16(vb), RNE
            }
            B0[et][kt] = __builtin_bit_cast(short8, w0);
        }
    }

    // ---- MFMA + epilogue, per qt (keeps D live-set at 16 VGPRs) ----
    const short8* pA0 = (const short8*)af0;

    float mp[4][Hd];
#pragma unroll
    for (int et = 0; et < 4; ++et)
#pragma unroll
        for (int i = 0; i < Hd; ++i) mp[et][i] = 0.0f;

#pragma unroll
    for (int qt = 0; qt < 4; ++qt) {
        // bias init: lane's D rows are q = qt*16 + 4g + r  ->  b2[qt*16+4g+r]
        float4 bb2 = *(const float4*)(b2 + qt * 16 + 4 * g);
        f32x4 D[4];
#pragma unroll
        for (int et = 0; et < 4; ++et) D[et] = (f32x4){bb2.x, bb2.y, bb2.z, bb2.w};

#pragma unroll
        for (int kt = 0; kt < 2; ++kt) {
            short8 a0 = pA0[(qt * 2 + kt) * 64 + lane];
#pragma unroll
            for (int et = 0; et < 4; ++et) {
                D[et] = __builtin_amdgcn_mfma_f32_16x16x32_bf16(a0, B0[et][kt], D[et], 0, 0, 0);
            }
        }

        // epilogue for this qt: relu + layer-3 partial dot
        const float4* w3p = (const float4*)(w3img + (qt * 64 + lane) * 20);
        float4 wa = w3p[0], wb = w3p[1], wc = w3p[2], wd = w3p[3], we = w3p[4];
        float w3s[4][5] = {
            { wa.x, wa.y, wa.z, wa.w, wb.x },
            { wb.y, wb.z, wb.w, wc.x, wc.y },
            { wc.z, wc.w, wd.x, wd.y, wd.z },
            { wd.w, we.x, we.y, we.z, we.w } };
#pragma unroll
        for (int et = 0; et < 4; ++et) {
#pragma unroll
            for (int r = 0; r < 4; ++r) {
                float a2v = fmaxf(D[et][r], 0.0f);
#pragma unroll
                for (int i = 0; i < Hd; ++i)
                    mp[et][i] = fmaf(a2v, w3s[r][i], mp[et][i]);
            }
        }
    }

    // reduce across the 4 lane-groups (same edge-col c, different out-rows)
#pragma unroll
    for (int et = 0; et < 4; ++et)
#pragma unroll
        for (int i = 0; i < Hd; ++i) {
            float v = mp[et][i];
            v += __shfl_xor(v, 16, 64);
            v += __shfl_xor(v, 32, 64);
            mp[et][i] = v;
        }

    // lane l's own edge = g*16 + c = lane  ->  pick et == g, add bias
    float m[Hd];
#pragma unroll
    for (int i = 0; i < Hd; ++i) {
        float v = (g == 0) ? mp[0][i] : (g == 1) ? mp[1][i] : (g == 2) ? mp[2][i] : mp[3][i];
        m[i] = v + b3[i];
    }

    // ---- wave segmented sum over sorted keys (verified round-5 code) ----
#pragma unroll
    for (int off = 1; off < 64; off <<= 1) {
        int ko = __shfl_up(io, off, 64);
        bool add = (lane >= off) && (ko == io);
#pragma unroll
        for (int i = 0; i < Hd; ++i) {
            float u = __shfl_up(m[i], off, 64);
            if (add) m[i] += u;
        }
    }
    int nk = __shfl_down(io, 1, 64);
    bool tail = (lane == 63) || (nk != io);
    if (tail) {
#pragma unroll
        for (int i = 0; i < Hd; ++i) atomicAdd(&sCur[hoff + i], m[i]);
    }
}

// ---------------------------------------------------------------------------
// per-node GRU update (unchanged, verified).
// ---------------------------------------------------------------------------
__global__ void node_kernel(
    const float* __restrict__ gzW, const float* __restrict__ gzb,
    const float* __restrict__ grW, const float* __restrict__ grb,
    const float* __restrict__ ghW, const float* __restrict__ ghb,
    float* __restrict__ h1, float* __restrict__ m0,
    float* __restrict__ s0buf, const float* __restrict__ s1buf,
    int zeroPrev)
{
    int t = blockIdx.x * 256 + threadIdx.x;
    if (t >= NBATCH * NN) return;
    size_t off = (size_t)t * Hd;

    float h1v[Hd], m0v[Hd], m1v[Hd];
#pragma unroll
    for (int i = 0; i < Hd; ++i) {
        h1v[i] = h1[off + i];
        float m0n = m0[off + i] + s0buf[off + i];
        m0v[i] = m0n;
        m1v[i] = m0n + s1buf[off + i];
        m0[off + i] = m0n;
        if (zeroPrev) s0buf[off + i] = 0.0f;
    }

    float a[15];
#pragma unroll
    for (int i = 0; i < Hd; ++i) { a[i] = h1v[i]; a[5 + i] = m0v[i]; a[10 + i] = m1v[i]; }

    float z[Hd], r[Hd];
#pragma unroll
    for (int i = 0; i < Hd; ++i) {
        float tz = gzb[i], tr = grb[i];
#pragma unroll
        for (int j = 0; j < 15; ++j) {
            tz = fmaf(a[j], gzW[j * Hd + i], tz);
            tr = fmaf(a[j], grW[j * Hd + i], tr);
        }
        z[i] = sigmoidf_(tz);
        r[i] = sigmoidf_(tr);
    }

    float joined[15];
#pragma unroll
    for (int i = 0; i < Hd; ++i) { joined[i] = r[i] * h1v[i]; joined[5 + i] = m0v[i]; joined[10 + i] = m1v[i]; }

#pragma unroll
    for (int i = 0; i < Hd; ++i) {
        float th = ghb[i];
#pragma unroll
        for (int j = 0; j < 15; ++j) th = fmaf(joined[j], ghW[j * Hd + i], th);
        float hh = tanhf(th);
        h1[off + i] = (1.0f - z[i]) * h1v[i] + z[i] * hh;
    }
}

// ---------------------------------------------------------------------------
// output MLP (unchanged, verified; runs once)
// ---------------------------------------------------------------------------
__global__ void __launch_bounds__(256, 1) out_kernel(
    const float* __restrict__ bnode, const float* __restrict__ h1,
    const float* __restrict__ oW1, const float* __restrict__ ob1,
    const float* __restrict__ oW2, const float* __restrict__ ob2,
    const float* __restrict__ oW3, const float* __restrict__ ob3,
    float* __restrict__ out)
{
    int t = blockIdx.x * 256 + threadIdx.x;
    if (t >= NBATCH * NN) return;

    float x[6];
#pragma unroll
    for (int i = 0; i < Hd; ++i) x[i] = h1[(size_t)t * Hd + i];
    x[5] = bnode[t];

    float acc[64];
#pragma unroll
    for (int q = 0; q < 64; ++q) acc[q] = ob2[q];

#pragma unroll 2
    for (int j = 0; j < 64; ++j) {
        float v = ob1[j];
#pragma unroll
        for (int f = 0; f < 6; ++f) v = fmaf(x[f], oW1[f * 64 + j], v);
        v = fmaxf(v, 0.0f);
        const float* __restrict__ w2r = oW2 + j * 64;
#pragma unroll
        for (int q = 0; q < 64; ++q) acc[q] = fmaf(v, w2r[q], acc[q]);
    }

    float o = ob3[0];
#pragma unroll
    for (int q = 0; q < 64; ++q) o = fmaf(fmaxf(acc[q], 0.0f), oW3[q], o);
    out[t] = sigmoidf_(o);
}

// ---------------------------------------------------------------------------
extern "C" void kernel_launch(void* const* d_in, const int* in_sizes, int n_in,
                              void* d_out, int out_size, void* d_ws, size_t ws_size,
                              hipStream_t stream) {
    const float* Jm    = (const float*)d_in[0];
    const float* bnode = (const float*)d_in[1];
    const int*   iin   = (const int*)d_in[2];
    const int*   iout  = (const int*)d_in[3];
    const float* mW1 = (const float*)d_in[4];
    const float* mb1 = (const float*)d_in[5];
    const float* mW2 = (const float*)d_in[6];
    const float* mb2 = (const float*)d_in[7];
    const float* mW3 = (const float*)d_in[8];
    const float* mb3 = (const float*)d_in[9];
    const float* gzW = (const float*)d_in[10];
    const float* gzb = (const float*)d_in[11];
    const float* grW = (const float*)d_in[12];
    const float* grb = (const float*)d_in[13];
    const float* ghW = (const float*)d_in[14];
    const float* ghb = (const float*)d_in[15];
    const float* oW1 = (const float*)d_in[16];
    const float* ob1 = (const float*)d_in[17];
    const float* oW2 = (const float*)d_in[18];
    const float* ob2 = (const float*)d_in[19];
    const float* oW3 = (const float*)d_in[20];
    const float* ob3 = (const float*)d_in[21];

    float* ws = (float*)d_ws;
    float* h1 = ws;
    float* m0 = ws + (size_t)BNH;
    float* sA = ws + (size_t)2 * BNH;
    float* sB = ws + (size_t)3 * BNH;
    unsigned* cnt  = (unsigned*)(ws + (size_t)4 * BNH);
    unsigned* cur  = cnt + NN;
    unsigned* row  = cur + NN;
    unsigned* perm = row + NN;
    int*      sout = (int*)(perm + EE);
    int*      sin  = sout + EE;
    float*    sJ   = (float*)(sin + EE);           // NBATCH*EE floats
    unsigned short* af0 = (unsigned short*)(sJ + (size_t)NBATCH * EE);  // 4096 bf16
    float*    w3img = (float*)(af0 + 4096);                             // 5120 floats

    // zero h1, m0, sA, sB, cnt, cur (contiguous)
    hipMemsetAsync(d_ws, 0, ((size_t)4 * BNH + 2 * NN) * sizeof(float), stream);

    // one-time (per launch): sort edges by index_out + build weight frag images
    k_hist<<<EE / 256, 256, 0, stream>>>(iout, cnt);
    k_scan<<<1, 256, 0, stream>>>(cnt, row);
    k_scatter<<<EE / 256, 256, 0, stream>>>(iout, row, cur, perm);
    k_mat<<<EE / 256, 256, 0, stream>>>(perm, iout, iin, Jm, sout, sin, sJ);
    k_wfrag<<<20, 256, 0, stream>>>(mW2, mW3, af0, w3img);

    dim3 mgrid(EE / 256, NBATCH);
    int ngrid = (NBATCH * NN + 255) / 256;

    float* buf[2] = { sA, sB };
    for (int s = 0; s < 10; ++s) {
        float* sCur  = buf[s & 1];
        float* sPrev = (s == 0) ? sCur : buf[(s + 1) & 1];
        msg_kernel<<<mgrid, 256, 0, stream>>>(sJ, bnode, sin, sout,
                                              mW1, mb1, af0, w3img,
                                              mb2, mb3, h1, sCur);
        node_kernel<<<ngrid, 256, 0, stream>>>(gzW, gzb, grW, grb, ghW, ghb,
                                               h1, m0, sPrev, sCur,
                                               (s == 0) ? 0 : 1);
    }

    out_kernel<<<ngrid, 256, 0, stream>>>(bnode, h1,
                                          oW1, ob1, oW2, ob2, oW3, ob3,
                                          (float*)d_out);
}

// Round 11
// 665.064 us; speedup vs baseline: 11.5473x; 1.3948x over previous
//
#include <hip/hip_runtime.h>
#include <hip/hip_bf16.h>
#include <math.h>

#define Hd 5
#define NN 20000
#define EE 320000
#define NBATCH 4
#define BNH (NBATCH * NN * Hd) /* 400000 */

typedef __attribute__((ext_vector_type(8))) short short8;
typedef __attribute__((ext_vector_type(4))) float f32x4;
typedef __attribute__((ext_vector_type(4))) unsigned int uint4v;

__device__ __forceinline__ float sigmoidf_(float v) {
    return 1.0f / (1.0f + expf(-v));
}

__device__ __forceinline__ unsigned short bf16bits(float v) {
    __hip_bfloat16 h = __float2bfloat16(v);
    return *(unsigned short*)&h;
}
__device__ __forceinline__ float bf16tof(unsigned short u) {
    __hip_bfloat16 h = *(__hip_bfloat16*)&u;
    return __bfloat162float(h);
}

// ===========================================================================
// one-time per-launch edge sort by index_out (counting sort) — verified r4/r5
// ===========================================================================
__global__ void k_hist(const int* __restrict__ iout, unsigned* __restrict__ cnt) {
    int t = blockIdx.x * 256 + threadIdx.x;
    atomicAdd(&cnt[iout[t]], 1u);
}

__global__ void k_scan(const unsigned* __restrict__ cnt, unsigned* __restrict__ row) {
    __shared__ unsigned part[256];
    int i = threadIdx.x;
    unsigned s = 0;
    if (i < 250) {
        for (int k = 0; k < 80; ++k) s += cnt[i * 80 + k];
    }
    part[i] = s;
    __syncthreads();
    for (int off = 1; off < 256; off <<= 1) {
        unsigned v = part[i];
        unsigned u = (i >= off) ? part[i - off] : 0u;
        __syncthreads();
        part[i] = v + u;
        __syncthreads();
    }
    unsigned run = (i == 0) ? 0u : part[i - 1];
    if (i < 250) {
        for (int k = 0; k < 80; ++k) {
            row[i * 80 + k] = run;
            run += cnt[i * 80 + k];
        }
    }
}

__global__ void k_scatter(const int* __restrict__ iout,
                          const unsigned* __restrict__ row,
                          unsigned* __restrict__ cur,
                          unsigned* __restrict__ perm) {
    int t = blockIdx.x * 256 + threadIdx.x;
    int io = iout[t];
    unsigned pos = row[io] + atomicAdd(&cur[io], 1u);
    perm[pos] = (unsigned)t;
}

__global__ void k_mat(const unsigned* __restrict__ perm,
                      const int* __restrict__ iout, const int* __restrict__ iin,
                      const float* __restrict__ Jm,
                      int* __restrict__ sout, int* __restrict__ sin,
                      float* __restrict__ sJ) {
    int t = blockIdx.x * 256 + threadIdx.x;
    unsigned e = perm[t];
    sout[t] = iout[e];
    sin[t]  = iin[e];
#pragma unroll
    for (int b = 0; b < NBATCH; ++b)
        sJ[(size_t)b * EE + t] = Jm[(size_t)b * EE + e];
}

// ===========================================================================
// prep: A-fragment images for BOTH MLP layers + w3img.
// Layer 1 (af1, 2048): one K=32 MFMA holds the full 4-term split product:
//   slot s=8g+j: A = (g<2 ? bf16(W1eff[j][q]) : bf16(resid))   q=qt*16+(l&15)
//   (B side supplies x_hi for even g, x_lo for odd g)
//   W1eff[7] = W1[7]-W1[8]  (folds the -jm feature)
// Layer 2 (af2, 4096): k-map chosen so layer-1's D output IS layer-2's B
//   fragment (no shuffles):  n(kt,g,j) = (j>>1)*16 + 4g + 2kt + (j&1)
//   af2[t], t=((qt*2+kt)*64+l)*8+j = bf16(W2[n][q]), q=qt*16+(l&15)
// w3img: [qt][l][r][i] = W3[(qt*16 + 4*(l>>4) + r)*5 + i]
// ===========================================================================
__global__ void k_wfrag(const float* __restrict__ W1, const float* __restrict__ W2,
                        const float* __restrict__ W3,
                        unsigned short* __restrict__ af1,
                        unsigned short* __restrict__ af2,
                        float* __restrict__ w3img) {
    int t = blockIdx.x * 256 + threadIdx.x;
    if (t < 2048) {
        int j  = t & 7;
        int l  = (t >> 3) & 63;
        int qt = t >> 9;
        int g  = l >> 4;
        int q  = qt * 16 + (l & 15);
        float base = (j < 7) ? W1[j * 64 + q] : (W1[7 * 64 + q] - W1[8 * 64 + q]);
        unsigned short w0 = bf16bits(base);
        af1[t] = (g < 2) ? w0 : bf16bits(base - bf16tof(w0));
    }
    if (t < 4096) {
        int j  = t & 7;
        int l  = (t >> 3) & 63;
        int kt = (t >> 9) & 1;
        int qt = t >> 10;
        int g  = l >> 4;
        int q  = qt * 16 + (l & 15);
        int n  = (j >> 1) * 16 + 4 * g + 2 * kt + (j & 1);
        af2[t] = bf16bits(W2[n * 64 + q]);
    }
    if (t < 5120) {
        int i  = t % 5;
        int r  = (t / 5) & 3;
        int l  = (t / 20) & 63;
        int qt = t / 1280;
        int q  = qt * 16 + 4 * (l >> 4) + r;
        w3img[t] = W3[q * 5 + i];
    }
}

// ===========================================================================
// MFMA message kernel. One wave = 64 sorted edges (one batch).
// Layer 1: ONE K=32 MFMA per (qt,et) — 4-term double-double split
//   (W0+Wr)(x0+x1) in the 32 k-slots; bias b1 via D-init. ~2^-17 accurate.
// Handoff: D1[qt][et] rows ARE layer-2 B slots under the af2 k-map:
//   B2[et][kt] dword qt = cvt_pk(relu(D1[qt][et][2kt]), relu(D1[qt][et][2kt+1]))
//   — no cross-lane ops.
// Layer 2: plain bf16 (r10-verified: absmax 1.95e-3), b2 via D-init.
// Epilogue/reduce/scan: r5/r10-verified code unchanged.
// grid: (EE/256, NBATCH), block 256 (4 waves), no LDS.
// ===========================================================================
__global__ void __launch_bounds__(256, 2) msg_kernel(
    const float* __restrict__ sJ, const float* __restrict__ bnode,
    const int* __restrict__ sin, const int* __restrict__ sout,
    const float* __restrict__ b1,
    const unsigned short* __restrict__ af1,
    const unsigned short* __restrict__ af2,
    const float* __restrict__ w3img, const float* __restrict__ b2,
    const float* __restrict__ b3,
    const float* __restrict__ h1,
    float* __restrict__ sCur)
{
    int wid  = threadIdx.x >> 6;
    int lane = threadIdx.x & 63;
    int g = lane >> 4;
    int c = lane & 15;
    int E0 = blockIdx.x * 256 + wid * 64;
    int bb = blockIdx.y;
    int e  = E0 + lane;

    int io = sout[e];
    int ii = sin[e];
    size_t hoff = ((size_t)bb * NN + io) * Hd;

    // own-edge features (broadcast sources); feature 7 = jm (weight folded)
    float xf[8];
#pragma unroll
    for (int i = 0; i < Hd; ++i) xf[i] = h1[hoff + i];
    xf[5] = bnode[bb * NN + ii];
    xf[6] = bnode[bb * NN + io];
    xf[7] = sJ[(size_t)bb * EE + e];

    // ---- build layer-1 B fragments: x_hi (trunc) / x_lo (residual, RNE) ----
    uint4v B1l[4];
#pragma unroll
    for (int et = 0; et < 4; ++et) {
        float xe[8];
#pragma unroll
        for (int f = 0; f < 8; ++f) xe[f] = __shfl(xf[f], et * 16 + c, 64);

        uint4v hiP, loP;
#pragma unroll
        for (int j2 = 0; j2 < 4; ++j2) {
            float va = xe[2 * j2], vb = xe[2 * j2 + 1];
            unsigned ta = __float_as_uint(va), tb = __float_as_uint(vb);
            unsigned ha = ta & 0xFFFF0000u, hb = tb & 0xFFFF0000u;
            hiP[j2] = hb | (ta >> 16);
            float ra = va - __uint_as_float(ha);
            float rb = vb - __uint_as_float(hb);
            unsigned pk;
            asm("v_cvt_pk_bf16_f32 %0, %1, %2" : "=v"(pk) : "v"(ra), "v"(rb));
            loP[j2] = pk;
        }
#pragma unroll
        for (int d = 0; d < 4; ++d) B1l[et][d] = (g & 1) ? loP[d] : hiP[d];
    }

    // ---- layer-1 MFMA: 4 qt x 4 et, one K=32 MFMA each, b1 in D-init ----
    const short8* pA1 = (const short8*)af1;
    f32x4 D1[4][4];
#pragma unroll
    for (int qt = 0; qt < 4; ++qt) {
        float4 bb1 = *(const float4*)(b1 + qt * 16 + 4 * g);
        short8 a1f = pA1[qt * 64 + lane];
#pragma unroll
        for (int et = 0; et < 4; ++et) {
            f32x4 dinit = (f32x4){bb1.x, bb1.y, bb1.z, bb1.w};
            D1[qt][et] = __builtin_amdgcn_mfma_f32_16x16x32_bf16(
                a1f, __builtin_bit_cast(short8, B1l[et]), dinit, 0, 0, 0);
        }
    }

    // ---- handoff: relu(D1) -> layer-2 B fragments (no shuffles) ----
    short8 B2[4][2];
#pragma unroll
    for (int et = 0; et < 4; ++et) {
        uint4v w0, w1;
#pragma unroll
        for (int qt = 0; qt < 4; ++qt) {
            float r0 = fmaxf(D1[qt][et][0], 0.0f);
            float r1 = fmaxf(D1[qt][et][1], 0.0f);
            float r2 = fmaxf(D1[qt][et][2], 0.0f);
            float r3 = fmaxf(D1[qt][et][3], 0.0f);
            unsigned p0, p1;
            asm("v_cvt_pk_bf16_f32 %0, %1, %2" : "=v"(p0) : "v"(r0), "v"(r1));
            asm("v_cvt_pk_bf16_f32 %0, %1, %2" : "=v"(p1) : "v"(r2), "v"(r3));
            w0[qt] = p0;
            w1[qt] = p1;
        }
        B2[et][0] = __builtin_bit_cast(short8, w0);
        B2[et][1] = __builtin_bit_cast(short8, w1);
    }

    // ---- layer-2 MFMA + epilogue, per qt (D live-set 16 VGPRs) ----
    const short8* pA2 = (const short8*)af2;

    float mp[4][Hd];
#pragma unroll
    for (int et = 0; et < 4; ++et)
#pragma unroll
        for (int i = 0; i < Hd; ++i) mp[et][i] = 0.0f;

#pragma unroll
    for (int qt = 0; qt < 4; ++qt) {
        float4 bb2 = *(const float4*)(b2 + qt * 16 + 4 * g);
        f32x4 D[4];
#pragma unroll
        for (int et = 0; et < 4; ++et) D[et] = (f32x4){bb2.x, bb2.y, bb2.z, bb2.w};

#pragma unroll
        for (int kt = 0; kt < 2; ++kt) {
            short8 a0 = pA2[(qt * 2 + kt) * 64 + lane];
#pragma unroll
            for (int et = 0; et < 4; ++et) {
                D[et] = __builtin_amdgcn_mfma_f32_16x16x32_bf16(a0, B2[et][kt], D[et], 0, 0, 0);
            }
        }

        const float4* w3p = (const float4*)(w3img + (qt * 64 + lane) * 20);
        float4 wa = w3p[0], wb = w3p[1], wc = w3p[2], wd = w3p[3], we = w3p[4];
        float w3s[4][5] = {
            { wa.x, wa.y, wa.z, wa.w, wb.x },
            { wb.y, wb.z, wb.w, wc.x, wc.y },
            { wc.z, wc.w, wd.x, wd.y, wd.z },
            { wd.w, we.x, we.y, we.z, we.w } };
#pragma unroll
        for (int et = 0; et < 4; ++et) {
#pragma unroll
            for (int r = 0; r < 4; ++r) {
                float a2v = fmaxf(D[et][r], 0.0f);
#pragma unroll
                for (int i = 0; i < Hd; ++i)
                    mp[et][i] = fmaf(a2v, w3s[r][i], mp[et][i]);
            }
        }
    }

    // reduce across the 4 lane-groups (same edge-col c, different out-rows)
#pragma unroll
    for (int et = 0; et < 4; ++et)
#pragma unroll
        for (int i = 0; i < Hd; ++i) {
            float v = mp[et][i];
            v += __shfl_xor(v, 16, 64);
            v += __shfl_xor(v, 32, 64);
            mp[et][i] = v;
        }

    // lane l's own edge = g*16 + c = lane  ->  pick et == g, add bias
    float m[Hd];
#pragma unroll
    for (int i = 0; i < Hd; ++i) {
        float v = (g == 0) ? mp[0][i] : (g == 1) ? mp[1][i] : (g == 2) ? mp[2][i] : mp[3][i];
        m[i] = v + b3[i];
    }

    // ---- wave segmented sum over sorted keys (verified round-5 code) ----
#pragma unroll
    for (int off = 1; off < 64; off <<= 1) {
        int ko = __shfl_up(io, off, 64);
        bool add = (lane >= off) && (ko == io);
#pragma unroll
        for (int i = 0; i < Hd; ++i) {
            float u = __shfl_up(m[i], off, 64);
            if (add) m[i] += u;
        }
    }
    int nk = __shfl_down(io, 1, 64);
    bool tail = (lane == 63) || (nk != io);
    if (tail) {
#pragma unroll
        for (int i = 0; i < Hd; ++i) atomicAdd(&sCur[hoff + i], m[i]);
    }
}

// ---------------------------------------------------------------------------
// per-node GRU update (unchanged, verified).
// ---------------------------------------------------------------------------
__global__ void node_kernel(
    const float* __restrict__ gzW, const float* __restrict__ gzb,
    const float* __restrict__ grW, const float* __restrict__ grb,
    const float* __restrict__ ghW, const float* __restrict__ ghb,
    float* __restrict__ h1, float* __restrict__ m0,
    float* __restrict__ s0buf, const float* __restrict__ s1buf,
    int zeroPrev)
{
    int t = blockIdx.x * 256 + threadIdx.x;
    if (t >= NBATCH * NN) return;
    size_t off = (size_t)t * Hd;

    float h1v[Hd], m0v[Hd], m1v[Hd];
#pragma unroll
    for (int i = 0; i < Hd; ++i) {
        h1v[i] = h1[off + i];
        float m0n = m0[off + i] + s0buf[off + i];
        m0v[i] = m0n;
        m1v[i] = m0n + s1buf[off + i];
        m0[off + i] = m0n;
        if (zeroPrev) s0buf[off + i] = 0.0f;
    }

    float a[15];
#pragma unroll
    for (int i = 0; i < Hd; ++i) { a[i] = h1v[i]; a[5 + i] = m0v[i]; a[10 + i] = m1v[i]; }

    float z[Hd], r[Hd];
#pragma unroll
    for (int i = 0; i < Hd; ++i) {
        float tz = gzb[i], tr = grb[i];
#pragma unroll
        for (int j = 0; j < 15; ++j) {
            tz = fmaf(a[j], gzW[j * Hd + i], tz);
            tr = fmaf(a[j], grW[j * Hd + i], tr);
        }
        z[i] = sigmoidf_(tz);
        r[i] = sigmoidf_(tr);
    }

    float joined[15];
#pragma unroll
    for (int i = 0; i < Hd; ++i) { joined[i] = r[i] * h1v[i]; joined[5 + i] = m0v[i]; joined[10 + i] = m1v[i]; }

#pragma unroll
    for (int i = 0; i < Hd; ++i) {
        float th = ghb[i];
#pragma unroll
        for (int j = 0; j < 15; ++j) th = fmaf(joined[j], ghW[j * Hd + i], th);
        float hh = tanhf(th);
        h1[off + i] = (1.0f - z[i]) * h1v[i] + z[i] * hh;
    }
}

// ---------------------------------------------------------------------------
// output MLP (unchanged, verified; runs once)
// ---------------------------------------------------------------------------
__global__ void __launch_bounds__(256, 1) out_kernel(
    const float* __restrict__ bnode, const float* __restrict__ h1,
    const float* __restrict__ oW1, const float* __restrict__ ob1,
    const float* __restrict__ oW2, const float* __restrict__ ob2,
    const float* __restrict__ oW3, const float* __restrict__ ob3,
    float* __restrict__ out)
{
    int t = blockIdx.x * 256 + threadIdx.x;
    if (t >= NBATCH * NN) return;

    float x[6];
#pragma unroll
    for (int i = 0; i < Hd; ++i) x[i] = h1[(size_t)t * Hd + i];
    x[5] = bnode[t];

    float acc[64];
#pragma unroll
    for (int q = 0; q < 64; ++q) acc[q] = ob2[q];

#pragma unroll 2
    for (int j = 0; j < 64; ++j) {
        float v = ob1[j];
#pragma unroll
        for (int f = 0; f < 6; ++f) v = fmaf(x[f], oW1[f * 64 + j], v);
        v = fmaxf(v, 0.0f);
        const float* __restrict__ w2r = oW2 + j * 64;
#pragma unroll
        for (int q = 0; q < 64; ++q) acc[q] = fmaf(v, w2r[q], acc[q]);
    }

    float o = ob3[0];
#pragma unroll
    for (int q = 0; q < 64; ++q) o = fmaf(fmaxf(acc[q], 0.0f), oW3[q], o);
    out[t] = sigmoidf_(o);
}

// ---------------------------------------------------------------------------
extern "C" void kernel_launch(void* const* d_in, const int* in_sizes, int n_in,
                              void* d_out, int out_size, void* d_ws, size_t ws_size,
                              hipStream_t stream) {
    const float* Jm    = (const float*)d_in[0];
    const float* bnode = (const float*)d_in[1];
    const int*   iin   = (const int*)d_in[2];
    const int*   iout  = (const int*)d_in[3];
    const float* mW1 = (const float*)d_in[4];
    const float* mb1 = (const float*)d_in[5];
    const float* mW2 = (const float*)d_in[6];
    const float* mb2 = (const float*)d_in[7];
    const float* mW3 = (const float*)d_in[8];
    const float* mb3 = (const float*)d_in[9];
    const float* gzW = (const float*)d_in[10];
    const float* gzb = (const float*)d_in[11];
    const float* grW = (const float*)d_in[12];
    const float* grb = (const float*)d_in[13];
    const float* ghW = (const float*)d_in[14];
    const float* ghb = (const float*)d_in[15];
    const float* oW1 = (const float*)d_in[16];
    const float* ob1 = (const float*)d_in[17];
    const float* oW2 = (const float*)d_in[18];
    const float* ob2 = (const float*)d_in[19];
    const float* oW3 = (const float*)d_in[20];
    const float* ob3 = (const float*)d_in[21];

    float* ws = (float*)d_ws;
    float* h1 = ws;
    float* m0 = ws + (size_t)BNH;
    float* sA = ws + (size_t)2 * BNH;
    float* sB = ws + (size_t)3 * BNH;
    unsigned* cnt  = (unsigned*)(ws + (size_t)4 * BNH);
    unsigned* cur  = cnt + NN;
    unsigned* row  = cur + NN;
    unsigned* perm = row + NN;
    int*      sout = (int*)(perm + EE);
    int*      sin  = sout + EE;
    float*    sJ   = (float*)(sin + EE);           // NBATCH*EE floats
    unsigned short* af1 = (unsigned short*)(sJ + (size_t)NBATCH * EE);  // 2048 bf16
    unsigned short* af2 = af1 + 2048;                                   // 4096 bf16
    float*    w3img = (float*)(af2 + 4096);                             // 5120 floats

    // zero h1, m0, sA, sB, cnt, cur (contiguous)
    hipMemsetAsync(d_ws, 0, ((size_t)4 * BNH + 2 * NN) * sizeof(float), stream);

    // one-time (per launch): sort edges by index_out + build weight frag images
    k_hist<<<EE / 256, 256, 0, stream>>>(iout, cnt);
    k_scan<<<1, 256, 0, stream>>>(cnt, row);
    k_scatter<<<EE / 256, 256, 0, stream>>>(iout, row, cur, perm);
    k_mat<<<EE / 256, 256, 0, stream>>>(perm, iout, iin, Jm, sout, sin, sJ);
    k_wfrag<<<20, 256, 0, stream>>>(mW1, mW2, mW3, af1, af2, w3img);

    dim3 mgrid(EE / 256, NBATCH);
    int ngrid = (NBATCH * NN + 255) / 256;

    float* buf[2] = { sA, sB };
    for (int s = 0; s < 10; ++s) {
        float* sCur  = buf[s & 1];
        float* sPrev = (s == 0) ? sCur : buf[(s + 1) & 1];
        msg_kernel<<<mgrid, 256, 0, stream>>>(sJ, bnode, sin, sout,
                                              mb1, af1, af2, w3img,
                                              mb2, mb3, h1, sCur);
        node_kernel<<<ngrid, 256, 0, stream>>>(gzW, gzb, grW, grb, ghW, ghb,
                                               h1, m0, sPrev, sCur,
                                               (s == 0) ? 0 : 1);
    }

    out_kernel<<<ngrid, 256, 0, stream>>>(bnode, h1,
                                          oW1, ob1, oW2, ob2, oW3, ob3,
                                          (float*)d_out);
}

// Round 12
// 513.713 us; speedup vs baseline: 14.9494x; 1.2946x over previous
//
#include <hip/hip_runtime.h>
#include <hip/hip_bf16.h>
#include <math.h>

#define Hd 5
#define NN 20000
#define EE 320000
#define NBATCH 4
#define BNH (NBATCH * NN * Hd) /* 400000 */

typedef __attribute__((ext_vector_type(8))) short short8;
typedef __attribute__((ext_vector_type(4))) float f32x4;
typedef __attribute__((ext_vector_type(4))) unsigned int uint4v;

__device__ __forceinline__ float sigmoidf_(float v) {
    return 1.0f / (1.0f + expf(-v));
}

__device__ __forceinline__ unsigned short bf16bits(float v) {
    __hip_bfloat16 h = __float2bfloat16(v);
    return *(unsigned short*)&h;
}
__device__ __forceinline__ float bf16tof(unsigned short u) {
    __hip_bfloat16 h = *(__hip_bfloat16*)&u;
    return __bfloat162float(h);
}

// ===========================================================================
// one-time per-launch edge sort by index_out (counting sort) — verified r4/r5
// ===========================================================================
__global__ void k_hist(const int* __restrict__ iout, unsigned* __restrict__ cnt) {
    int t = blockIdx.x * 256 + threadIdx.x;
    atomicAdd(&cnt[iout[t]], 1u);
}

__global__ void k_scan(const unsigned* __restrict__ cnt, unsigned* __restrict__ row) {
    __shared__ unsigned part[256];
    int i = threadIdx.x;
    unsigned s = 0;
    if (i < 250) {
        for (int k = 0; k < 80; ++k) s += cnt[i * 80 + k];
    }
    part[i] = s;
    __syncthreads();
    for (int off = 1; off < 256; off <<= 1) {
        unsigned v = part[i];
        unsigned u = (i >= off) ? part[i - off] : 0u;
        __syncthreads();
        part[i] = v + u;
        __syncthreads();
    }
    unsigned run = (i == 0) ? 0u : part[i - 1];
    if (i < 250) {
        for (int k = 0; k < 80; ++k) {
            row[i * 80 + k] = run;
            run += cnt[i * 80 + k];
        }
    }
}

__global__ void k_scatter(const int* __restrict__ iout,
                          const unsigned* __restrict__ row,
                          unsigned* __restrict__ cur,
                          unsigned* __restrict__ perm) {
    int t = blockIdx.x * 256 + threadIdx.x;
    int io = iout[t];
    unsigned pos = row[io] + atomicAdd(&cur[io], 1u);
    perm[pos] = (unsigned)t;
}

__global__ void k_mat(const unsigned* __restrict__ perm,
                      const int* __restrict__ iout, const int* __restrict__ iin,
                      const float* __restrict__ Jm,
                      int* __restrict__ sout, int* __restrict__ sin,
                      float* __restrict__ sJ) {
    int t = blockIdx.x * 256 + threadIdx.x;
    unsigned e = perm[t];
    sout[t] = iout[e];
    sin[t]  = iin[e];
#pragma unroll
    for (int b = 0; b < NBATCH; ++b)
        sJ[(size_t)b * EE + t] = Jm[(size_t)b * EE + e];
}

// ===========================================================================
// prep: A-fragment images for ALL THREE MLP layers.
// Layer 1 (af1, 2048): K=32 MFMA holds 4-term split (W0+Wr)(x0+x1):
//   slot 8g+j: A = (g<2 ? bf16(W1eff[j][q]) : resid), q=qt*16+(l&15)
//   W1eff[7] = W1[7]-W1[8] (folds -jm).
// Layer 2 (af2, 4096): k-map n_k(kt,g,j) = (j>>1)*16+4g+2kt+(j&1) matches
//   layer-1's D output (r11-verified).  NEW out-map (free relabeling):
//   n_out(qt,p) = (qt&1)*32 + 8*(p>>2) + 4*(qt>>1) + (p&3), p = D row pos,
//   chosen so D2 rows of qt-pair {kt,kt+2} ARE layer-3 B slots k=kt*32+8g+j.
// Layer 3 (af3, 1024): A row i=(l&15) (out channel, rows 5..15 zero),
//   k-slot (kt,g,j) -> neuron n = kt*32+8g+j (same map as B side).
// ===========================================================================
__global__ void k_wfrag(const float* __restrict__ W1, const float* __restrict__ W2,
                        const float* __restrict__ W3,
                        unsigned short* __restrict__ af1,
                        unsigned short* __restrict__ af2,
                        unsigned short* __restrict__ af3) {
    int t = blockIdx.x * 256 + threadIdx.x;
    if (t < 2048) {
        int j  = t & 7;
        int l  = (t >> 3) & 63;
        int qt = t >> 9;
        int g  = l >> 4;
        int q  = qt * 16 + (l & 15);
        float base = (j < 7) ? W1[j * 64 + q] : (W1[7 * 64 + q] - W1[8 * 64 + q]);
        unsigned short w0 = bf16bits(base);
        af1[t] = (g < 2) ? w0 : bf16bits(base - bf16tof(w0));
    }
    if (t < 4096) {
        int j  = t & 7;
        int l  = (t >> 3) & 63;
        int kt = (t >> 9) & 1;
        int qt = t >> 10;
        int g  = l >> 4;
        int p  = l & 15;
        int nk = (j >> 1) * 16 + 4 * g + 2 * kt + (j & 1);
        int no = (qt & 1) * 32 + 8 * (p >> 2) + 4 * (qt >> 1) + (p & 3);
        af2[t] = bf16bits(W2[nk * 64 + no]);
    }
    if (t < 1024) {
        int j  = t & 7;
        int l  = (t >> 3) & 63;
        int kt = t >> 9;
        int i  = l & 15;
        int g3 = l >> 4;
        int n  = kt * 32 + 8 * g3 + j;
        af3[t] = (i < 5) ? bf16bits(W3[n * 5 + i]) : (unsigned short)0;
    }
}

// ===========================================================================
// MFMA message kernel — ALL THREE layers on the matrix pipe.
// Layer 1: 16 MFMA (4-term split, b1 via D-init) -> handoff (relu+cvt_pk,
//   no shuffles, r11-verified) -> Layer 2: 32 MFMA in qt-pairs {half,half+2}
//   (b2 via D-init at relabeled rows half*32+8g+{0..7}) -> handoff -> Layer 3:
//   8 MFMA produce Z3[5][64 edges] (K=64 contraction replaces shfl reduce).
// Redistribution: edge g*16+c pulls rows 0-3 from lane c, row 4 from lane
//   16+c (20 bpermute + selects), + b3.
// Scan/atomics: r5-verified segmented sum unchanged.
// grid: (EE/256, NBATCH), block 256 (4 waves), no LDS.
// ===========================================================================
__global__ void __launch_bounds__(256, 2) msg_kernel(
    const float* __restrict__ sJ, const float* __restrict__ bnode,
    const int* __restrict__ sin, const int* __restrict__ sout,
    const float* __restrict__ b1,
    const unsigned short* __restrict__ af1,
    const unsigned short* __restrict__ af2,
    const unsigned short* __restrict__ af3,
    const float* __restrict__ b2, const float* __restrict__ b3,
    const float* __restrict__ h1,
    float* __restrict__ sCur)
{
    int wid  = threadIdx.x >> 6;
    int lane = threadIdx.x & 63;
    int g = lane >> 4;
    int c = lane & 15;
    int E0 = blockIdx.x * 256 + wid * 64;
    int bb = blockIdx.y;
    int e  = E0 + lane;

    int io = sout[e];
    int ii = sin[e];
    size_t hoff = ((size_t)bb * NN + io) * Hd;

    // own-edge features (broadcast sources); feature 7 = jm (weight folded)
    float xf[8];
#pragma unroll
    for (int i = 0; i < Hd; ++i) xf[i] = h1[hoff + i];
    xf[5] = bnode[bb * NN + ii];
    xf[6] = bnode[bb * NN + io];
    xf[7] = sJ[(size_t)bb * EE + e];

    // ---- build layer-1 B fragments: x_hi (trunc) / x_lo (residual, RNE) ----
    uint4v B1l[4];
#pragma unroll
    for (int et = 0; et < 4; ++et) {
        float xe[8];
#pragma unroll
        for (int f = 0; f < 8; ++f) xe[f] = __shfl(xf[f], et * 16 + c, 64);

        uint4v hiP, loP;
#pragma unroll
        for (int j2 = 0; j2 < 4; ++j2) {
            float va = xe[2 * j2], vb = xe[2 * j2 + 1];
            unsigned ta = __float_as_uint(va), tb = __float_as_uint(vb);
            unsigned ha = ta & 0xFFFF0000u, hb = tb & 0xFFFF0000u;
            hiP[j2] = hb | (ta >> 16);
            float ra = va - __uint_as_float(ha);
            float rb = vb - __uint_as_float(hb);
            unsigned pk;
            asm("v_cvt_pk_bf16_f32 %0, %1, %2" : "=v"(pk) : "v"(ra), "v"(rb));
            loP[j2] = pk;
        }
#pragma unroll
        for (int d = 0; d < 4; ++d) B1l[et][d] = (g & 1) ? loP[d] : hiP[d];
    }

    // ---- layer-1 MFMA: 4 qt x 4 et, one K=32 MFMA each, b1 in D-init ----
    const short8* pA1 = (const short8*)af1;
    f32x4 D1[4][4];
#pragma unroll
    for (int qt = 0; qt < 4; ++qt) {
        float4 bb1 = *(const float4*)(b1 + qt * 16 + 4 * g);
        short8 a1f = pA1[qt * 64 + lane];
#pragma unroll
        for (int et = 0; et < 4; ++et) {
            f32x4 dinit = (f32x4){bb1.x, bb1.y, bb1.z, bb1.w};
            D1[qt][et] = __builtin_amdgcn_mfma_f32_16x16x32_bf16(
                a1f, __builtin_bit_cast(short8, B1l[et]), dinit, 0, 0, 0);
        }
    }

    // ---- handoff: relu(D1) -> layer-2 B fragments (no shuffles) ----
    short8 B2[4][2];
#pragma unroll
    for (int et = 0; et < 4; ++et) {
        uint4v w0, w1;
#pragma unroll
        for (int qt = 0; qt < 4; ++qt) {
            float r0 = fmaxf(D1[qt][et][0], 0.0f);
            float r1 = fmaxf(D1[qt][et][1], 0.0f);
            float r2 = fmaxf(D1[qt][et][2], 0.0f);
            float r3 = fmaxf(D1[qt][et][3], 0.0f);
            unsigned p0, p1;
            asm("v_cvt_pk_bf16_f32 %0, %1, %2" : "=v"(p0) : "v"(r0), "v"(r1));
            asm("v_cvt_pk_bf16_f32 %0, %1, %2" : "=v"(p1) : "v"(r2), "v"(r3));
            w0[qt] = p0;
            w1[qt] = p1;
        }
        B2[et][0] = __builtin_bit_cast(short8, w0);
        B2[et][1] = __builtin_bit_cast(short8, w1);
    }

    // ---- layers 2+3 in qt-pairs {half, half+2}; D3 accumulates over half ----
    const short8* pA2 = (const short8*)af2;
    const short8* pA3 = (const short8*)af3;

    f32x4 D3[4];
#pragma unroll
    for (int et = 0; et < 4; ++et) D3[et] = (f32x4){0.f, 0.f, 0.f, 0.f};

#pragma unroll
    for (int half = 0; half < 2; ++half) {
        // b2 at relabeled rows: D2a rows = half*32+8g+{0..3}, D2b = +{4..7}
        float4 ba  = *(const float4*)(b2 + half * 32 + 8 * g);
        float4 bbv = *(const float4*)(b2 + half * 32 + 8 * g + 4);
        f32x4 D2a[4], D2b[4];
#pragma unroll
        for (int et = 0; et < 4; ++et) {
            D2a[et] = (f32x4){ba.x, ba.y, ba.z, ba.w};
            D2b[et] = (f32x4){bbv.x, bbv.y, bbv.z, bbv.w};
        }
#pragma unroll
        for (int kt2 = 0; kt2 < 2; ++kt2) {
            short8 a0a = pA2[(half * 2 + kt2) * 64 + lane];
            short8 a0b = pA2[((half + 2) * 2 + kt2) * 64 + lane];
#pragma unroll
            for (int et = 0; et < 4; ++et) {
                D2a[et] = __builtin_amdgcn_mfma_f32_16x16x32_bf16(a0a, B2[et][kt2], D2a[et], 0, 0, 0);
                D2b[et] = __builtin_amdgcn_mfma_f32_16x16x32_bf16(a0b, B2[et][kt2], D2b[et], 0, 0, 0);
            }
        }
        // handoff: relu(D2 pair) -> layer-3 B fragment for k-tile `half`
        short8 a3 = pA3[half * 64 + lane];
#pragma unroll
        for (int et = 0; et < 4; ++et) {
            float x0 = fmaxf(D2a[et][0], 0.0f), x1 = fmaxf(D2a[et][1], 0.0f);
            float x2 = fmaxf(D2a[et][2], 0.0f), x3 = fmaxf(D2a[et][3], 0.0f);
            float y0 = fmaxf(D2b[et][0], 0.0f), y1 = fmaxf(D2b[et][1], 0.0f);
            float y2 = fmaxf(D2b[et][2], 0.0f), y3 = fmaxf(D2b[et][3], 0.0f);
            uint4v pk;
            unsigned p0, p1, p2, p3;
            asm("v_cvt_pk_bf16_f32 %0, %1, %2" : "=v"(p0) : "v"(x0), "v"(x1));
            asm("v_cvt_pk_bf16_f32 %0, %1, %2" : "=v"(p1) : "v"(x2), "v"(x3));
            asm("v_cvt_pk_bf16_f32 %0, %1, %2" : "=v"(p2) : "v"(y0), "v"(y1));
            asm("v_cvt_pk_bf16_f32 %0, %1, %2" : "=v"(p3) : "v"(y2), "v"(y3));
            pk[0] = p0; pk[1] = p1; pk[2] = p2; pk[3] = p3;
            D3[et] = __builtin_amdgcn_mfma_f32_16x16x32_bf16(
                a3, __builtin_bit_cast(short8, pk), D3[et], 0, 0, 0);
        }
    }

    // ---- redistribution: edge g*16+c <- rows 0-3 @ lane c, row 4 @ 16+c ----
    float m[Hd];
#pragma unroll
    for (int i = 0; i < 4; ++i) {
        float p0 = __shfl(D3[0][i], c, 64);
        float p1 = __shfl(D3[1][i], c, 64);
        float p2 = __shfl(D3[2][i], c, 64);
        float p3 = __shfl(D3[3][i], c, 64);
        m[i] = ((g == 0) ? p0 : (g == 1) ? p1 : (g == 2) ? p2 : p3) + b3[i];
    }
    {
        float p0 = __shfl(D3[0][0], 16 + c, 64);
        float p1 = __shfl(D3[1][0], 16 + c, 64);
        float p2 = __shfl(D3[2][0], 16 + c, 64);
        float p3 = __shfl(D3[3][0], 16 + c, 64);
        m[4] = ((g == 0) ? p0 : (g == 1) ? p1 : (g == 2) ? p2 : p3) + b3[4];
    }

    // ---- wave segmented sum over sorted keys (verified round-5 code) ----
#pragma unroll
    for (int off = 1; off < 64; off <<= 1) {
        int ko = __shfl_up(io, off, 64);
        bool add = (lane >= off) && (ko == io);
#pragma unroll
        for (int i = 0; i < Hd; ++i) {
            float u = __shfl_up(m[i], off, 64);
            if (add) m[i] += u;
        }
    }
    int nk = __shfl_down(io, 1, 64);
    bool tail = (lane == 63) || (nk != io);
    if (tail) {
#pragma unroll
        for (int i = 0; i < Hd; ++i) atomicAdd(&sCur[hoff + i], m[i]);
    }
}

// ---------------------------------------------------------------------------
// per-node GRU update (unchanged, verified).
// ---------------------------------------------------------------------------
__global__ void node_kernel(
    const float* __restrict__ gzW, const float* __restrict__ gzb,
    const float* __restrict__ grW, const float* __restrict__ grb,
    const float* __restrict__ ghW, const float* __restrict__ ghb,
    float* __restrict__ h1, float* __restrict__ m0,
    float* __restrict__ s0buf, const float* __restrict__ s1buf,
    int zeroPrev)
{
    int t = blockIdx.x * 256 + threadIdx.x;
    if (t >= NBATCH * NN) return;
    size_t off = (size_t)t * Hd;

    float h1v[Hd], m0v[Hd], m1v[Hd];
#pragma unroll
    for (int i = 0; i < Hd; ++i) {
        h1v[i] = h1[off + i];
        float m0n = m0[off + i] + s0buf[off + i];
        m0v[i] = m0n;
        m1v[i] = m0n + s1buf[off + i];
        m0[off + i] = m0n;
        if (zeroPrev) s0buf[off + i] = 0.0f;
    }

    float a[15];
#pragma unroll
    for (int i = 0; i < Hd; ++i) { a[i] = h1v[i]; a[5 + i] = m0v[i]; a[10 + i] = m1v[i]; }

    float z[Hd], r[Hd];
#pragma unroll
    for (int i = 0; i < Hd; ++i) {
        float tz = gzb[i], tr = grb[i];
#pragma unroll
        for (int j = 0; j < 15; ++j) {
            tz = fmaf(a[j], gzW[j * Hd + i], tz);
            tr = fmaf(a[j], grW[j * Hd + i], tr);
        }
        z[i] = sigmoidf_(tz);
        r[i] = sigmoidf_(tr);
    }

    float joined[15];
#pragma unroll
    for (int i = 0; i < Hd; ++i) { joined[i] = r[i] * h1v[i]; joined[5 + i] = m0v[i]; joined[10 + i] = m1v[i]; }

#pragma unroll
    for (int i = 0; i < Hd; ++i) {
        float th = ghb[i];
#pragma unroll
        for (int j = 0; j < 15; ++j) th = fmaf(joined[j], ghW[j * Hd + i], th);
        float hh = tanhf(th);
        h1[off + i] = (1.0f - z[i]) * h1v[i] + z[i] * hh;
    }
}

// ---------------------------------------------------------------------------
// output MLP (unchanged, verified; runs once)
// ---------------------------------------------------------------------------
__global__ void __launch_bounds__(256, 1) out_kernel(
    const float* __restrict__ bnode, const float* __restrict__ h1,
    const float* __restrict__ oW1, const float* __restrict__ ob1,
    const float* __restrict__ oW2, const float* __restrict__ ob2,
    const float* __restrict__ oW3, const float* __restrict__ ob3,
    float* __restrict__ out)
{
    int t = blockIdx.x * 256 + threadIdx.x;
    if (t >= NBATCH * NN) return;

    float x[6];
#pragma unroll
    for (int i = 0; i < Hd; ++i) x[i] = h1[(size_t)t * Hd + i];
    x[5] = bnode[t];

    float acc[64];
#pragma unroll
    for (int q = 0; q < 64; ++q) acc[q] = ob2[q];

#pragma unroll 2
    for (int j = 0; j < 64; ++j) {
        float v = ob1[j];
#pragma unroll
        for (int f = 0; f < 6; ++f) v = fmaf(x[f], oW1[f * 64 + j], v);
        v = fmaxf(v, 0.0f);
        const float* __restrict__ w2r = oW2 + j * 64;
#pragma unroll
        for (int q = 0; q < 64; ++q) acc[q] = fmaf(v, w2r[q], acc[q]);
    }

    float o = ob3[0];
#pragma unroll
    for (int q = 0; q < 64; ++q) o = fmaf(fmaxf(acc[q], 0.0f), oW3[q], o);
    out[t] = sigmoidf_(o);
}

// ---------------------------------------------------------------------------
extern "C" void kernel_launch(void* const* d_in, const int* in_sizes, int n_in,
                              void* d_out, int out_size, void* d_ws, size_t ws_size,
                              hipStream_t stream) {
    const float* Jm    = (const float*)d_in[0];
    const float* bnode = (const float*)d_in[1];
    const int*   iin   = (const int*)d_in[2];
    const int*   iout  = (const int*)d_in[3];
    const float* mW1 = (const float*)d_in[4];
    const float* mb1 = (const float*)d_in[5];
    const float* mW2 = (const float*)d_in[6];
    const float* mb2 = (const float*)d_in[7];
    const float* mW3 = (const float*)d_in[8];
    const float* mb3 = (const float*)d_in[9];
    const float* gzW = (const float*)d_in[10];
    const float* gzb = (const float*)d_in[11];
    const float* grW = (const float*)d_in[12];
    const float* grb = (const float*)d_in[13];
    const float* ghW = (const float*)d_in[14];
    const float* ghb = (const float*)d_in[15];
    const float* oW1 = (const float*)d_in[16];
    const float* ob1 = (const float*)d_in[17];
    const float* oW2 = (const float*)d_in[18];
    const float* ob2 = (const float*)d_in[19];
    const float* oW3 = (const float*)d_in[20];
    const float* ob3 = (const float*)d_in[21];

    float* ws = (float*)d_ws;
    float* h1 = ws;
    float* m0 = ws + (size_t)BNH;
    float* sA = ws + (size_t)2 * BNH;
    float* sB = ws + (size_t)3 * BNH;
    unsigned* cnt  = (unsigned*)(ws + (size_t)4 * BNH);
    unsigned* cur  = cnt + NN;
    unsigned* row  = cur + NN;
    unsigned* perm = row + NN;
    int*      sout = (int*)(perm + EE);
    int*      sin  = sout + EE;
    float*    sJ   = (float*)(sin + EE);           // NBATCH*EE floats
    unsigned short* af1 = (unsigned short*)(sJ + (size_t)NBATCH * EE);  // 2048
    unsigned short* af2 = af1 + 2048;                                   // 4096
    unsigned short* af3 = af2 + 4096;                                   // 1024

    // zero h1, m0, sA, sB, cnt, cur (contiguous)
    hipMemsetAsync(d_ws, 0, ((size_t)4 * BNH + 2 * NN) * sizeof(float), stream);

    // one-time (per launch): sort edges by index_out + build weight frag images
    k_hist<<<EE / 256, 256, 0, stream>>>(iout, cnt);
    k_scan<<<1, 256, 0, stream>>>(cnt, row);
    k_scatter<<<EE / 256, 256, 0, stream>>>(iout, row, cur, perm);
    k_mat<<<EE / 256, 256, 0, stream>>>(perm, iout, iin, Jm, sout, sin, sJ);
    k_wfrag<<<20, 256, 0, stream>>>(mW1, mW2, mW3, af1, af2, af3);

    dim3 mgrid(EE / 256, NBATCH);
    int ngrid = (NBATCH * NN + 255) / 256;

    float* buf[2] = { sA, sB };
    for (int s = 0; s < 10; ++s) {
        float* sCur  = buf[s & 1];
        float* sPrev = (s == 0) ? sCur : buf[(s + 1) & 1];
        msg_kernel<<<mgrid, 256, 0, stream>>>(sJ, bnode, sin, sout,
                                              mb1, af1, af2, af3,
                                              mb2, mb3, h1, sCur);
        node_kernel<<<ngrid, 256, 0, stream>>>(gzW, gzb, grW, grb, ghW, ghb,
                                               h1, m0, sPrev, sCur,
                                               (s == 0) ? 0 : 1);
    }

    out_kernel<<<ngrid, 256, 0, stream>>>(bnode, h1,
                                          oW1, ob1, oW2, ob2, oW3, ob3,
                                          (float*)d_out);
}